// Round 5
// baseline (207.762 us; speedup 1.0000x reference)
//
#include <hip/hip_runtime.h>
#include <math.h>

#define PI_F 3.14159265358979323846f
#define NPIX 262144  // 512*512

__device__ __forceinline__ float2 cmul(float2 a, float2 b) {
    return make_float2(a.x * b.x - a.y * b.y, a.x * b.y + a.y * b.x);
}
__device__ __forceinline__ float2 cadd(float2 a, float2 b) {
    return make_float2(a.x + b.x, a.y + b.y);
}
__device__ __forceinline__ float2 csub(float2 a, float2 b) {
    return make_float2(a.x - b.x, a.y - b.y);
}

// twiddle table: tw[m] = exp(DIR * 2*pi*i * m / 512), m in [0,384)
template<int DIR>
__device__ __forceinline__ void fill_tw(float2* tw, int t) {
    for (int m = t; m < 384; m += 128) {
        float s, c;
        sincosf((float)DIR * (2.0f * PI_F) * (float)m * (1.0f / 512.0f), &s, &c);
        tw[m] = make_float2(c, s);
    }
}

// ---------------------------------------------------------------------------
// 512-pt Stockham autosort FFT in LDS: 4 radix-4 stages + 1 radix-2 stage.
// 128 threads; caller must __syncthreads() after filling sA and tw.
// Returns pointer to the result buffer (= sB). Inverse is unnormalized.
// Hand-verified against DFT-4 for both DIR; ping-pong parity checked
// (4 swaps -> X==sA at radix-2 entry, result lands in sB).
// ---------------------------------------------------------------------------
template<int DIR>
__device__ __forceinline__ float2* fft512(float2* sA, float2* sB,
                                          const float2* tw, int t) {
    float2* X = sA;
    float2* Y = sB;
    int Ns = 1;
#pragma unroll
    for (int s = 0; s < 4; ++s) {  // Ns = 1, 4, 16, 64
        const int jm = t & (Ns - 1);
        const int jd = t - jm;
        float2 v0 = X[t], v1 = X[t + 128], v2 = X[t + 256], v3 = X[t + 384];
        const int m1 = jm * (128 / Ns);  // jm*N/(4*Ns) twiddle exponent step
        v1 = cmul(tw[m1], v1);
        v2 = cmul(tw[2 * m1], v2);
        v3 = cmul(tw[3 * m1], v3);
        const float2 t0 = cadd(v0, v2), t1 = csub(v0, v2);
        const float2 t2 = cadd(v1, v3), t3 = csub(v1, v3);
        // DIR*i*t3
        const float2 t3i = (DIR > 0) ? make_float2(-t3.y, t3.x)
                                     : make_float2(t3.y, -t3.x);
        const int od = (jd << 2) + jm;  // expand(j, Ns, 4)
        Y[od]          = cadd(t0, t2);
        Y[od + Ns]     = cadd(t1, t3i);
        Y[od + 2 * Ns] = csub(t0, t2);
        Y[od + 3 * Ns] = csub(t1, t3i);
        __syncthreads();
        float2* tmp = X; X = Y; Y = tmp;
        Ns <<= 2;
    }
    // final radix-2 stage, Ns = 256: Y[j] = X[j] +- tw[j]*X[j+256], j<256
#pragma unroll
    for (int q = 0; q < 2; ++q) {
        const int j = t + q * 128;
        const float2 a = X[j], b = X[j + 256];
        const float2 tt = cmul(tw[j], b);
        Y[j]       = cadd(a, tt);
        Y[j + 256] = csub(a, tt);
    }
    __syncthreads();
    return Y;
}

// ---------------------------------------------------------------------------
// Forward pass 1 for the 12 y/phi images, fused with complex packing:
// row FFT of (y + i*phi/w[b]). One block per (img,row). float4 loads.
// ---------------------------------------------------------------------------
__global__ __launch_bounds__(128) void fwd_fft_pack(const float* __restrict__ y,
                                                    const float* __restrict__ phi,
                                                    const float* __restrict__ w,
                                                    float2* __restrict__ S) {
    __shared__ float2 sA[512], sB[512], tw[384];
    const int t = threadIdx.x;
    const int img = blockIdx.x >> 9, row = blockIdx.x & 511;
    fill_tw<-1>(tw, t);
    const size_t off = (size_t)img * NPIX + (size_t)row * 512;
    const float iwv = 1.0f / w[img / 3];
    const float4 yv = ((const float4*)(y + off))[t];
    const float4 pv = ((const float4*)(phi + off))[t];
    sA[4 * t + 0] = make_float2(yv.x, pv.x * iwv);
    sA[4 * t + 1] = make_float2(yv.y, pv.y * iwv);
    sA[4 * t + 2] = make_float2(yv.z, pv.z * iwv);
    sA[4 * t + 3] = make_float2(yv.w, pv.w * iwv);
    __syncthreads();
    float2* R = fft512<-1>(sA, sB, tw, t);
    float4* wp = (float4*)(S + off);
    for (int k = t; k < 256; k += 128)
        wp[k] = make_float4(R[2 * k].x, R[2 * k].y,
                            R[2 * k + 1].x, R[2 * k + 1].y);
}

// ---------------------------------------------------------------------------
// Forward pass 1 for K (4 imgs, 25 nonzero rows each) and G (3 imgs, 9 rows):
// in-place row FFT of only the nonzero rows (rest stay zero). 127 blocks.
// ---------------------------------------------------------------------------
__global__ __launch_bounds__(128) void fwd_fft_kg(float2* __restrict__ S) {
    __shared__ float2 sA[512], sB[512], tw[384];
    const int t = threadIdx.x;
    int img, row;
    if (blockIdx.x < 100) {
        img = 12 + (int)blockIdx.x / 25;
        row = ((int)blockIdx.x % 25 - 12) & 511;
    } else {
        const int g = (int)blockIdx.x - 100;
        img = 16 + g / 9;
        row = ((g % 9) - 4) & 511;
    }
    fill_tw<-1>(tw, t);
    float2* rp = S + (size_t)img * NPIX + (size_t)row * 512;
    for (int k = t; k < 512; k += 128) sA[k] = rp[k];
    __syncthreads();
    float2* R = fft512<-1>(sA, sB, tw, t);
    for (int k = t; k < 512; k += 128) rp[k] = R[k];
}

// ---------------------------------------------------------------------------
// Generic in-place row FFT, one block per row (grid = n_imgs*512).
// float4 (2-complex) vectorized global load/store.
// ---------------------------------------------------------------------------
template<int DIR>
__global__ __launch_bounds__(128) void fft_rows(float2* __restrict__ D) {
    __shared__ float2 sA[512], sB[512], tw[384];
    const int t = threadIdx.x;
    fill_tw<DIR>(tw, t);
    float2* rp = D + (size_t)blockIdx.x * 512;
    const float4* rp4 = (const float4*)rp;
    for (int k = t; k < 256; k += 128) {
        const float4 v = rp4[k];
        sA[2 * k]     = make_float2(v.x, v.y);
        sA[2 * k + 1] = make_float2(v.z, v.w);
    }
    __syncthreads();
    float2* R = fft512<DIR>(sA, sB, tw, t);
    float4* wp = (float4*)rp;
    for (int k = t; k < 256; k += 128)
        wp[k] = make_float4(R[2 * k].x, R[2 * k].y,
                            R[2 * k + 1].x, R[2 * k + 1].y);
}

// ---------------------------------------------------------------------------
// Inverse pass 2 fused with real unpack: row FFT then write Re->img 2p,
// Im->img 2p+1, scaled by 1/N^2. One block per (pair,row). float4 stores.
// ---------------------------------------------------------------------------
__global__ __launch_bounds__(128) void inv_fft_unpack(const float2* __restrict__ T,
                                                      float* __restrict__ out) {
    __shared__ float2 sA[512], sB[512], tw[384];
    const int t = threadIdx.x;
    const int pair = blockIdx.x >> 9, row = blockIdx.x & 511;
    fill_tw<1>(tw, t);
    const float2* rp = T + (size_t)pair * NPIX + (size_t)row * 512;
    const float4* rp4 = (const float4*)rp;
    for (int k = t; k < 256; k += 128) {
        const float4 v = rp4[k];
        sA[2 * k]     = make_float2(v.x, v.y);
        sA[2 * k + 1] = make_float2(v.z, v.w);
    }
    __syncthreads();
    float2* R = fft512<1>(sA, sB, tw, t);
    const float sc = 1.0f / 262144.0f;
    float* o0 = out + (size_t)(2 * pair) * NPIX + (size_t)row * 512;
    float* o1 = o0 + NPIX;
    ((float4*)o0)[t] = make_float4(R[4 * t].x * sc, R[4 * t + 1].x * sc,
                                   R[4 * t + 2].x * sc, R[4 * t + 3].x * sc);
    ((float4*)o1)[t] = make_float4(R[4 * t].y * sc, R[4 * t + 1].y * sc,
                                   R[4 * t + 2].y * sc, R[4 * t + 3].y * sc);
}

// ---------------------------------------------------------------------------
// IN-PLACE 512x512 transpose per image (blockIdx.z): tile-pair swap.
// Block (bi,bj) with bi<=bj loads tiles (bj,bi) and (bi,bj), writes each
// transposed into the other; diagonal tiles transpose in place. Blocks with
// bi>bj exit immediately. tile stride 33 -> only 2-way bank aliasing (free).
// ---------------------------------------------------------------------------
__global__ __launch_bounds__(256) void transpose512_inplace(float2* __restrict__ D) {
    if (blockIdx.x > blockIdx.y) return;
    __shared__ float2 tA[32][33], tB[32][33];
    const size_t base = (size_t)blockIdx.z * NPIX;
    const int bi = blockIdx.x * 32, bj = blockIdx.y * 32;
    const int tx = threadIdx.x, ty = threadIdx.y;  // (32, 8)
    const bool diag = (bi == bj);
#pragma unroll
    for (int j = 0; j < 32; j += 8)
        tA[ty + j][tx] = D[base + (size_t)(bj + ty + j) * 512 + bi + tx];
    if (!diag) {
#pragma unroll
        for (int j = 0; j < 32; j += 8)
            tB[ty + j][tx] = D[base + (size_t)(bi + ty + j) * 512 + bj + tx];
    }
    __syncthreads();
#pragma unroll
    for (int j = 0; j < 32; j += 8)
        D[base + (size_t)(bi + ty + j) * 512 + bj + tx] = tA[tx][ty + j];
    if (!diag) {
#pragma unroll
        for (int j = 0; j < 32; j += 8)
            D[base + (size_t)(bj + ty + j) * 512 + bi + tx] = tB[tx][ty + j];
    }
}

// ---------------------------------------------------------------------------
// Out-of-place 512x512 transpose per image (blockIdx.z), 32x32 tiles.
// Used only on the 6-image inverse path (dst = then-dead forward buffer).
// ---------------------------------------------------------------------------
__global__ __launch_bounds__(256) void transpose512(const float2* __restrict__ in,
                                                    float2* __restrict__ out) {
    __shared__ float2 tile[32][33];
    const size_t base = (size_t)blockIdx.z * NPIX;
    const int bx = blockIdx.x * 32, by = blockIdx.y * 32;
    const int tx = threadIdx.x, ty = threadIdx.y;  // (32, 8)
#pragma unroll
    for (int j = 0; j < 32; j += 8)
        tile[ty + j][tx] = in[base + (size_t)(by + ty + j) * 512 + bx + tx];
    __syncthreads();
#pragma unroll
    for (int j = 0; j < 32; j += 8)
        out[base + (size_t)(bx + ty + j) * 512 + by + tx] = tile[tx][ty + j];
}

// ---------------------------------------------------------------------------
// Sparse inputs: pad+roll k (25x25, shift -12) into imgs 12..15, and the
// per-channel summed autocorrelation of weights (9x9 support; circular shift
// cancels in |FFT|^2) into imgs 16..18. Region must be pre-zeroed.
// ---------------------------------------------------------------------------
__global__ __launch_bounds__(256) void prep_kg(const float* __restrict__ kin,
                                               const float* __restrict__ wts,
                                               float2* __restrict__ S) {
    const int t = blockIdx.x * 256 + threadIdx.x;
    if (t < 2500) {
        const int b = t / 625, rem = t % 625;
        const int i = rem / 25, j = rem % 25;
        const int r = (i - 12) & 511, c = (j - 12) & 511;
        S[(size_t)(12 + b) * NPIX + (size_t)r * 512 + c] =
            make_float2(kin[t], 0.0f);
    } else if (t < 2743) {
        const int q = t - 2500;
        const int ch = q / 81, rem = q % 81;
        const int di = rem / 9 - 4, dj = rem % 9 - 4;
        float acc = 0.0f;
        for (int f = 0; f < 24; ++f) {
            const float* g = wts + (size_t)(f * 3 + ch) * 25;
#pragma unroll
        for (int x = 0; x < 5; ++x) {
                const int x2 = x + di;
                if (x2 < 0 || x2 >= 5) continue;
#pragma unroll
                for (int yy = 0; yy < 5; ++yy) {
                    const int y2 = yy + dj;
                    if (y2 < 0 || y2 >= 5) continue;
                    acc += g[x * 5 + yy] * g[x2 * 5 + y2];
                }
            }
        }
        const int r = di & 511, c = dj & 511;
        S[(size_t)(16 + ch) * NPIX + (size_t)r * 512 + c] =
            make_float2(acc, 0.0f);
    }
}

// ---------------------------------------------------------------------------
// Wiener combine: Hermitian-unpack Z (imgs 0..11 of S) into Fy/Fphi, apply
// Omega filter with Dk (imgs 12..15) and real Dg autocorr spectra (16..18),
// pack image pairs into 6 complex spectra written to P (disjoint from S).
// All spectra share the same transposed layout; index negation commutes
// with transpose.
// ---------------------------------------------------------------------------
__global__ __launch_bounds__(256) void combine_pack(const float2* __restrict__ S,
                                                    const float* __restrict__ w,
                                                    float2* __restrict__ P) {
    const int p = blockIdx.x * 256 + threadIdx.x;  // < NPIX
    const int pair = blockIdx.y;                   // 0..5
    const int r = p >> 9, c = p & 511;
    const int np = (((512 - r) & 511) << 9) | ((512 - c) & 511);
    float2 num[2];
#pragma unroll
    for (int e = 0; e < 2; ++e) {
        const int img = pair * 2 + e;
        const int b = img / 3;
        const int ch = img - 3 * b;
        const float2* Zi = S + (size_t)img * NPIX;
        const float2 Zv = Zi[p];
        const float2 Zn = Zi[np];
        const float2 Zm = make_float2(Zn.x, -Zn.y);  // conj(Z(-u))
        const float2 Fy = make_float2(0.5f * (Zv.x + Zm.x),
                                      0.5f * (Zv.y + Zm.y));
        const float dx = Zv.x - Zm.x, dy = Zv.y - Zm.y;
        const float2 Fphi = make_float2(0.5f * dy, -0.5f * dx);  // -i/2*(Zv-Zm)
        const float2 K = S[(size_t)(12 + b) * NPIX + p];
        const float kk = K.x * K.x + K.y * K.y;
        const float dg = S[(size_t)(16 + ch) * NPIX + p].x / w[b];
        const float Om = 1.0f / (kk + dg);
        const float2 tt = make_float2(K.x * Fy.x + K.y * Fy.y,
                                      K.x * Fy.y - K.y * Fy.x);  // conj(K)*Fy
        num[e] = make_float2(Om * (tt.x + Fphi.x), Om * (tt.y + Fphi.y));
    }
    // P = num0 + i*num1  (both ifft2 results are real -> unpack later)
    P[(size_t)pair * NPIX + p] =
        make_float2(num[0].x - num[1].y, num[0].y + num[1].x);
}

// ---------------------------------------------------------------------------
extern "C" void kernel_launch(void* const* d_in, const int* in_sizes, int n_in,
                              void* d_out, int out_size, void* d_ws, size_t ws_size,
                              hipStream_t stream) {
    const float* y   = (const float*)d_in[0];
    const float* k   = (const float*)d_in[1];
    const float* w   = (const float*)d_in[2];
    const float* phi = (const float*)d_in[3];
    const float* wts = (const float*)d_in[4];
    float* out = (float*)d_out;

    // workspace: S = 19 images (12 y/phi + 4 K + 3 G) + P = 6 images. 50 MB.
    const size_t needed = (size_t)25 * NPIX * sizeof(float2);
    if (ws_size < needed) return;  // clean incorrectness signal, never OOB
    float2* S = (float2*)d_ws;
    float2* P = S + (size_t)19 * NPIX;

    // zero only the sparse K/G region (imgs 12..18)
    hipMemsetAsync(S + (size_t)12 * NPIX, 0,
                   (size_t)7 * NPIX * sizeof(float2), stream);

    prep_kg<<<11, 256, 0, stream>>>(k, wts, S);
    fwd_fft_pack<<<12 * 512, 128, 0, stream>>>(y, phi, w, S);
    fwd_fft_kg<<<127, 128, 0, stream>>>(S);

    dim3 tb(32, 8);
    transpose512_inplace<<<dim3(16, 16, 19), tb, 0, stream>>>(S);
    fft_rows<-1><<<19 * 512, 128, 0, stream>>>(S);

    combine_pack<<<dim3(1024, 6), 256, 0, stream>>>(S, w, P);

    fft_rows<1><<<6 * 512, 128, 0, stream>>>(P);
    transpose512<<<dim3(16, 16, 6), tb, 0, stream>>>(P, S);  // S[0..5] now free
    inv_fft_unpack<<<6 * 512, 128, 0, stream>>>(S, out);
}

// Round 6
// 164.942 us; speedup vs baseline: 1.2596x; 1.2596x over previous
//
#include <hip/hip_runtime.h>
#include <math.h>

#define PI_F 3.14159265358979323846f
#define NPIX 262144  // 512*512

__device__ __forceinline__ float2 cmul(float2 a, float2 b) {
    return make_float2(a.x * b.x - a.y * b.y, a.x * b.y + a.y * b.x);
}
__device__ __forceinline__ float2 cadd(float2 a, float2 b) {
    return make_float2(a.x + b.x, a.y + b.y);
}
__device__ __forceinline__ float2 csub(float2 a, float2 b) {
    return make_float2(a.x - b.x, a.y - b.y);
}

// twiddle table: tw[m] = exp(DIR * 2*pi*i * m / 512), m in [0,384)
template<int DIR>
__device__ __forceinline__ void fill_tw(float2* tw, int t) {
    for (int m = t; m < 384; m += 128) {
        float s, c;
        sincosf((float)DIR * (2.0f * PI_F) * (float)m * (1.0f / 512.0f), &s, &c);
        tw[m] = make_float2(c, s);
    }
}

// ---------------------------------------------------------------------------
// 512-pt Stockham autosort FFT in LDS: 4 radix-4 stages + 1 radix-2 stage.
// 128 threads; caller must __syncthreads() after filling sA and tw.
// Returns pointer to the result buffer (= sB). Inverse is unnormalized.
// ---------------------------------------------------------------------------
template<int DIR>
__device__ __forceinline__ float2* fft512(float2* sA, float2* sB,
                                          const float2* tw, int t) {
    float2* X = sA;
    float2* Y = sB;
    int Ns = 1;
#pragma unroll
    for (int s = 0; s < 4; ++s) {  // Ns = 1, 4, 16, 64
        const int jm = t & (Ns - 1);
        const int jd = t - jm;
        float2 v0 = X[t], v1 = X[t + 128], v2 = X[t + 256], v3 = X[t + 384];
        const int m1 = jm * (128 / Ns);  // jm*N/(4*Ns) twiddle exponent step
        v1 = cmul(tw[m1], v1);
        v2 = cmul(tw[2 * m1], v2);
        v3 = cmul(tw[3 * m1], v3);
        const float2 t0 = cadd(v0, v2), t1 = csub(v0, v2);
        const float2 t2 = cadd(v1, v3), t3 = csub(v1, v3);
        // DIR*i*t3
        const float2 t3i = (DIR > 0) ? make_float2(-t3.y, t3.x)
                                     : make_float2(t3.y, -t3.x);
        const int od = (jd << 2) + jm;  // expand(j, Ns, 4)
        Y[od]          = cadd(t0, t2);
        Y[od + Ns]     = cadd(t1, t3i);
        Y[od + 2 * Ns] = csub(t0, t2);
        Y[od + 3 * Ns] = csub(t1, t3i);
        __syncthreads();
        float2* tmp = X; X = Y; Y = tmp;
        Ns <<= 2;
    }
    // final radix-2 stage, Ns = 256: Y[j] = X[j] +- tw[j]*X[j+256], j<256
#pragma unroll
    for (int q = 0; q < 2; ++q) {
        const int j = t + q * 128;
        const float2 a = X[j], b = X[j + 256];
        const float2 tt = cmul(tw[j], b);
        Y[j]       = cadd(a, tt);
        Y[j + 256] = csub(a, tt);
    }
    __syncthreads();
    return Y;
}

// ---------------------------------------------------------------------------
// Forward pass 1 for the 12 y/phi images, fused with complex packing:
// row FFT of (y + i*phi/w[b]). One block per (img,row). float4 loads.
// ---------------------------------------------------------------------------
__global__ __launch_bounds__(128) void fwd_fft_pack(const float* __restrict__ y,
                                                    const float* __restrict__ phi,
                                                    const float* __restrict__ w,
                                                    float2* __restrict__ S) {
    __shared__ float2 sA[512], sB[512], tw[384];
    const int t = threadIdx.x;
    const int img = blockIdx.x >> 9, row = blockIdx.x & 511;
    fill_tw<-1>(tw, t);
    const size_t off = (size_t)img * NPIX + (size_t)row * 512;
    const float iwv = 1.0f / w[img / 3];
    const float4 yv = ((const float4*)(y + off))[t];
    const float4 pv = ((const float4*)(phi + off))[t];
    sA[4 * t + 0] = make_float2(yv.x, pv.x * iwv);
    sA[4 * t + 1] = make_float2(yv.y, pv.y * iwv);
    sA[4 * t + 2] = make_float2(yv.z, pv.z * iwv);
    sA[4 * t + 3] = make_float2(yv.w, pv.w * iwv);
    __syncthreads();
    float2* R = fft512<-1>(sA, sB, tw, t);
    float4* wp = (float4*)(S + off);
    for (int k = t; k < 256; k += 128)
        wp[k] = make_float4(R[2 * k].x, R[2 * k].y,
                            R[2 * k + 1].x, R[2 * k + 1].y);
}

// ---------------------------------------------------------------------------
// Forward pass 1 for K (4 imgs, 25 nonzero rows each) and G (3 imgs, 9 rows):
// in-place row FFT of only the nonzero rows (rest stay zero). 127 blocks.
// ---------------------------------------------------------------------------
__global__ __launch_bounds__(128) void fwd_fft_kg(float2* __restrict__ S) {
    __shared__ float2 sA[512], sB[512], tw[384];
    const int t = threadIdx.x;
    int img, row;
    if (blockIdx.x < 100) {
        img = 12 + (int)blockIdx.x / 25;
        row = ((int)blockIdx.x % 25 - 12) & 511;
    } else {
        const int g = (int)blockIdx.x - 100;
        img = 16 + g / 9;
        row = ((g % 9) - 4) & 511;
    }
    fill_tw<-1>(tw, t);
    float2* rp = S + (size_t)img * NPIX + (size_t)row * 512;
    for (int k = t; k < 512; k += 128) sA[k] = rp[k];
    __syncthreads();
    float2* R = fft512<-1>(sA, sB, tw, t);
    for (int k = t; k < 512; k += 128) rp[k] = R[k];
}

// ---------------------------------------------------------------------------
// Generic in-place row FFT, one block per row (grid = n_imgs*512).
// float4 (2-complex) vectorized global load/store.
// ---------------------------------------------------------------------------
template<int DIR>
__global__ __launch_bounds__(128) void fft_rows(float2* __restrict__ D) {
    __shared__ float2 sA[512], sB[512], tw[384];
    const int t = threadIdx.x;
    fill_tw<DIR>(tw, t);
    float2* rp = D + (size_t)blockIdx.x * 512;
    const float4* rp4 = (const float4*)rp;
    for (int k = t; k < 256; k += 128) {
        const float4 v = rp4[k];
        sA[2 * k]     = make_float2(v.x, v.y);
        sA[2 * k + 1] = make_float2(v.z, v.w);
    }
    __syncthreads();
    float2* R = fft512<DIR>(sA, sB, tw, t);
    float4* wp = (float4*)rp;
    for (int k = t; k < 256; k += 128)
        wp[k] = make_float4(R[2 * k].x, R[2 * k].y,
                            R[2 * k + 1].x, R[2 * k + 1].y);
}

// ---------------------------------------------------------------------------
// Inverse pass 2 fused with real unpack: row FFT then write Re->img 2p,
// Im->img 2p+1, scaled by 1/N^2. One block per (pair,row). float4 stores.
// ---------------------------------------------------------------------------
__global__ __launch_bounds__(128) void inv_fft_unpack(const float2* __restrict__ T,
                                                      float* __restrict__ out) {
    __shared__ float2 sA[512], sB[512], tw[384];
    const int t = threadIdx.x;
    const int pair = blockIdx.x >> 9, row = blockIdx.x & 511;
    fill_tw<1>(tw, t);
    const float2* rp = T + (size_t)pair * NPIX + (size_t)row * 512;
    const float4* rp4 = (const float4*)rp;
    for (int k = t; k < 256; k += 128) {
        const float4 v = rp4[k];
        sA[2 * k]     = make_float2(v.x, v.y);
        sA[2 * k + 1] = make_float2(v.z, v.w);
    }
    __syncthreads();
    float2* R = fft512<1>(sA, sB, tw, t);
    const float sc = 1.0f / 262144.0f;
    float* o0 = out + (size_t)(2 * pair) * NPIX + (size_t)row * 512;
    float* o1 = o0 + NPIX;
    ((float4*)o0)[t] = make_float4(R[4 * t].x * sc, R[4 * t + 1].x * sc,
                                   R[4 * t + 2].x * sc, R[4 * t + 3].x * sc);
    ((float4*)o1)[t] = make_float4(R[4 * t].y * sc, R[4 * t + 1].y * sc,
                                   R[4 * t + 2].y * sc, R[4 * t + 3].y * sc);
}

// ---------------------------------------------------------------------------
// IN-PLACE 512x512 transpose per image (blockIdx.z): tile-pair swap.
// ---------------------------------------------------------------------------
__global__ __launch_bounds__(256) void transpose512_inplace(float2* __restrict__ D) {
    if (blockIdx.x > blockIdx.y) return;
    __shared__ float2 tA[32][33], tB[32][33];
    const size_t base = (size_t)blockIdx.z * NPIX;
    const int bi = blockIdx.x * 32, bj = blockIdx.y * 32;
    const int tx = threadIdx.x, ty = threadIdx.y;  // (32, 8)
    const bool diag = (bi == bj);
#pragma unroll
    for (int j = 0; j < 32; j += 8)
        tA[ty + j][tx] = D[base + (size_t)(bj + ty + j) * 512 + bi + tx];
    if (!diag) {
#pragma unroll
        for (int j = 0; j < 32; j += 8)
            tB[ty + j][tx] = D[base + (size_t)(bi + ty + j) * 512 + bj + tx];
    }
    __syncthreads();
#pragma unroll
    for (int j = 0; j < 32; j += 8)
        D[base + (size_t)(bi + ty + j) * 512 + bj + tx] = tA[tx][ty + j];
    if (!diag) {
#pragma unroll
        for (int j = 0; j < 32; j += 8)
            D[base + (size_t)(bj + ty + j) * 512 + bi + tx] = tB[tx][ty + j];
    }
}

// ---------------------------------------------------------------------------
// Out-of-place 512x512 transpose per image (blockIdx.z), 32x32 tiles.
// Used only on the 6-image inverse path (dst = then-dead forward buffer).
// ---------------------------------------------------------------------------
__global__ __launch_bounds__(256) void transpose512(const float2* __restrict__ in,
                                                    float2* __restrict__ out) {
    __shared__ float2 tile[32][33];
    const size_t base = (size_t)blockIdx.z * NPIX;
    const int bx = blockIdx.x * 32, by = blockIdx.y * 32;
    const int tx = threadIdx.x, ty = threadIdx.y;  // (32, 8)
#pragma unroll
    for (int j = 0; j < 32; j += 8)
        tile[ty + j][tx] = in[base + (size_t)(by + ty + j) * 512 + bx + tx];
    __syncthreads();
#pragma unroll
    for (int j = 0; j < 32; j += 8)
        out[base + (size_t)(bx + ty + j) * 512 + by + tx] = tile[tx][ty + j];
}

// ---------------------------------------------------------------------------
// Sparse-input prep, parallel + branch-free version.
// Blocks 0..9: pad+roll k (25x25, shift -12) into imgs 12..15.
// Blocks 10..12 (one per channel ch): summed autocorrelation of weights into
// imgs 16..18. Weights staged in LDS zero-padded to 13x13 per filter, so the
// shifted read gp[f][x+di+4][y+dj+4] is always in-bounds -> NO divergent
// conditionals in the MAC loop (the round-5 51.7us came from a divergent-CFG-
// serialized ~200-cyc load chain: 600 bodies x 206 cyc measured).
// Thread = (dpos, f-segment): 243 threads x 200 branch-free LDS MACs, then a
// 3-way deterministic LDS reduction. Target region must be pre-zeroed.
// ---------------------------------------------------------------------------
__global__ __launch_bounds__(256) void prep_kg(const float* __restrict__ kin,
                                               const float* __restrict__ wts,
                                               float2* __restrict__ S) {
    const int bid = blockIdx.x, tid = threadIdx.x;
    if (bid < 10) {  // k padding: t < 2500
        const int t = bid * 256 + tid;
        if (t < 2500) {
            const int b = t / 625, rem = t % 625;
            const int i = rem / 25, j = rem % 25;
            const int r = (i - 12) & 511, c = (j - 12) & 511;
            S[(size_t)(12 + b) * NPIX + (size_t)r * 512 + c] =
                make_float2(kin[t], 0.0f);
        }
        return;
    }
    const int ch = bid - 10;  // 0..2
    __shared__ float gp[24][13][13];  // 5x5 filter zero-padded at [4..8][4..8]
    __shared__ float part[243];
    float* gpf = &gp[0][0][0];
    for (int i = tid; i < 24 * 169; i += 256) gpf[i] = 0.0f;
    __syncthreads();
    for (int i = tid; i < 600; i += 256) {
        const int f = i / 25, rem = i % 25;
        const int x = rem / 5, yy = rem % 5;
        gp[f][x + 4][yy + 4] = wts[(size_t)(f * 3 + ch) * 25 + rem];
    }
    __syncthreads();
    if (tid < 243) {
        const int dpos = tid / 3, seg = tid % 3;  // seg covers 8 filters
        const int di = dpos / 9 - 4, dj = dpos % 9 - 4;
        float acc = 0.0f;
        for (int f = seg * 8; f < seg * 8 + 8; ++f) {
#pragma unroll
            for (int x = 0; x < 5; ++x)
#pragma unroll
                for (int yy = 0; yy < 5; ++yy)
                    acc += gp[f][x + 4][yy + 4] *
                           gp[f][x + di + 4][yy + dj + 4];
        }
        part[tid] = acc;
    }
    __syncthreads();
    if (tid < 81) {
        const float a = part[tid * 3] + part[tid * 3 + 1] + part[tid * 3 + 2];
        const int di = tid / 9 - 4, dj = tid % 9 - 4;
        const int r = di & 511, c = dj & 511;
        S[(size_t)(16 + ch) * NPIX + (size_t)r * 512 + c] =
            make_float2(a, 0.0f);
    }
}

// ---------------------------------------------------------------------------
// Wiener combine: Hermitian-unpack Z (imgs 0..11 of S) into Fy/Fphi, apply
// Omega filter with Dk (imgs 12..15) and real Dg autocorr spectra (16..18),
// pack image pairs into 6 complex spectra written to P (disjoint from S).
// ---------------------------------------------------------------------------
__global__ __launch_bounds__(256) void combine_pack(const float2* __restrict__ S,
                                                    const float* __restrict__ w,
                                                    float2* __restrict__ P) {
    const int p = blockIdx.x * 256 + threadIdx.x;  // < NPIX
    const int pair = blockIdx.y;                   // 0..5
    const int r = p >> 9, c = p & 511;
    const int np = (((512 - r) & 511) << 9) | ((512 - c) & 511);
    float2 num[2];
#pragma unroll
    for (int e = 0; e < 2; ++e) {
        const int img = pair * 2 + e;
        const int b = img / 3;
        const int ch = img - 3 * b;
        const float2* Zi = S + (size_t)img * NPIX;
        const float2 Zv = Zi[p];
        const float2 Zn = Zi[np];
        const float2 Zm = make_float2(Zn.x, -Zn.y);  // conj(Z(-u))
        const float2 Fy = make_float2(0.5f * (Zv.x + Zm.x),
                                      0.5f * (Zv.y + Zm.y));
        const float dx = Zv.x - Zm.x, dy = Zv.y - Zm.y;
        const float2 Fphi = make_float2(0.5f * dy, -0.5f * dx);  // -i/2*(Zv-Zm)
        const float2 K = S[(size_t)(12 + b) * NPIX + p];
        const float kk = K.x * K.x + K.y * K.y;
        const float dg = S[(size_t)(16 + ch) * NPIX + p].x / w[b];
        const float Om = 1.0f / (kk + dg);
        const float2 tt = make_float2(K.x * Fy.x + K.y * Fy.y,
                                      K.x * Fy.y - K.y * Fy.x);  // conj(K)*Fy
        num[e] = make_float2(Om * (tt.x + Fphi.x), Om * (tt.y + Fphi.y));
    }
    // P = num0 + i*num1  (both ifft2 results are real -> unpack later)
    P[(size_t)pair * NPIX + p] =
        make_float2(num[0].x - num[1].y, num[0].y + num[1].x);
}

// ---------------------------------------------------------------------------
extern "C" void kernel_launch(void* const* d_in, const int* in_sizes, int n_in,
                              void* d_out, int out_size, void* d_ws, size_t ws_size,
                              hipStream_t stream) {
    const float* y   = (const float*)d_in[0];
    const float* k   = (const float*)d_in[1];
    const float* w   = (const float*)d_in[2];
    const float* phi = (const float*)d_in[3];
    const float* wts = (const float*)d_in[4];
    float* out = (float*)d_out;

    // workspace: S = 19 images (12 y/phi + 4 K + 3 G) + P = 6 images. 50 MB.
    const size_t needed = (size_t)25 * NPIX * sizeof(float2);
    if (ws_size < needed) return;  // clean incorrectness signal, never OOB
    float2* S = (float2*)d_ws;
    float2* P = S + (size_t)19 * NPIX;

    // zero only the sparse K/G region (imgs 12..18)
    hipMemsetAsync(S + (size_t)12 * NPIX, 0,
                   (size_t)7 * NPIX * sizeof(float2), stream);

    prep_kg<<<13, 256, 0, stream>>>(k, wts, S);
    fwd_fft_pack<<<12 * 512, 128, 0, stream>>>(y, phi, w, S);
    fwd_fft_kg<<<127, 128, 0, stream>>>(S);

    dim3 tb(32, 8);
    transpose512_inplace<<<dim3(16, 16, 19), tb, 0, stream>>>(S);
    fft_rows<-1><<<19 * 512, 128, 0, stream>>>(S);

    combine_pack<<<dim3(1024, 6), 256, 0, stream>>>(S, w, P);

    fft_rows<1><<<6 * 512, 128, 0, stream>>>(P);
    transpose512<<<dim3(16, 16, 6), tb, 0, stream>>>(P, S);  // S[0..5] now free
    inv_fft_unpack<<<6 * 512, 128, 0, stream>>>(S, out);
}

// Round 9
// 159.439 us; speedup vs baseline: 1.3031x; 1.0345x over previous
//
#include <hip/hip_runtime.h>
#include <math.h>

#define PI_F 3.14159265358979323846f
#define NPIX 262144  // 512*512

__device__ __forceinline__ float2 cmul(float2 a, float2 b) {
    return make_float2(a.x * b.x - a.y * b.y, a.x * b.y + a.y * b.x);
}
__device__ __forceinline__ float2 cadd(float2 a, float2 b) {
    return make_float2(a.x + b.x, a.y + b.y);
}
__device__ __forceinline__ float2 csub(float2 a, float2 b) {
    return make_float2(a.x - b.x, a.y - b.y);
}

// twiddle table: tw[m] = exp(DIR * 2*pi*i * m / 512), m in [0,384).
// Angles are exact multiples of 2pi/512, |ang| < 1.5pi -> native __sinf/__cosf
// (v_sin/v_cos) are accurate here; avoids libm sincosf (~50 instr + branches).
template<int DIR>
__device__ __forceinline__ void fill_tw(float2* tw, int t, int stride) {
    for (int m = t; m < 384; m += stride) {
        const float ang = (2.0f * PI_F / 512.0f) * (float)m;
        const float s = __sinf(ang), c = __cosf(ang);
        tw[m] = make_float2(c, (DIR > 0) ? s : -s);
    }
}

// ---------------------------------------------------------------------------
// 512-pt Stockham autosort FFT in LDS: 4 radix-4 stages + 1 radix-2 stage.
// 128 worker lanes (t in [0,128)); caller syncs after filling sA and tw.
// Returns pointer to result buffer (= sB). Inverse is unnormalized.
// ---------------------------------------------------------------------------
template<int DIR>
__device__ __forceinline__ float2* fft512(float2* sA, float2* sB,
                                          const float2* tw, int t) {
    float2* X = sA;
    float2* Y = sB;
    int Ns = 1;
#pragma unroll
    for (int s = 0; s < 4; ++s) {  // Ns = 1, 4, 16, 64
        const int jm = t & (Ns - 1);
        const int jd = t - jm;
        float2 v0 = X[t], v1 = X[t + 128], v2 = X[t + 256], v3 = X[t + 384];
        const int m1 = jm * (128 / Ns);
        v1 = cmul(tw[m1], v1);
        v2 = cmul(tw[2 * m1], v2);
        v3 = cmul(tw[3 * m1], v3);
        const float2 t0 = cadd(v0, v2), t1 = csub(v0, v2);
        const float2 t2 = cadd(v1, v3), t3 = csub(v1, v3);
        const float2 t3i = (DIR > 0) ? make_float2(-t3.y, t3.x)
                                     : make_float2(t3.y, -t3.x);
        const int od = (jd << 2) + jm;  // expand(j, Ns, 4)
        Y[od]          = cadd(t0, t2);
        Y[od + Ns]     = cadd(t1, t3i);
        Y[od + 2 * Ns] = csub(t0, t2);
        Y[od + 3 * Ns] = csub(t1, t3i);
        __syncthreads();
        float2* tmp = X; X = Y; Y = tmp;
        Ns <<= 2;
    }
#pragma unroll
    for (int q = 0; q < 2; ++q) {  // final radix-2, Ns = 256
        const int j = t + q * 128;
        const float2 a = X[j], b = X[j + 256];
        const float2 tt = cmul(tw[j], b);
        Y[j]       = cadd(a, tt);
        Y[j + 256] = csub(a, tt);
    }
    __syncthreads();
    return Y;
}

// ---------------------------------------------------------------------------
// Forward pass 1, merged: blocks 0..6143 = row FFT of (y + i*phi/w[b]) for
// the 12 y/phi images (fused packing, float4 loads); blocks 6144..6270 =
// in-place row FFT of the 127 nonzero K/G rows (prep_kg output).
// ---------------------------------------------------------------------------
__global__ __launch_bounds__(128) void fwd_fft_all(const float* __restrict__ y,
                                                   const float* __restrict__ phi,
                                                   const float* __restrict__ w,
                                                   float2* __restrict__ S) {
    __shared__ float2 sA[512], sB[512], tw[384];
    const int t = threadIdx.x;
    fill_tw<-1>(tw, t, 128);
    if (blockIdx.x < 6144) {
        const int img = blockIdx.x >> 9, row = blockIdx.x & 511;
        const size_t off = (size_t)img * NPIX + (size_t)row * 512;
        const float iwv = 1.0f / w[img / 3];
        const float4 yv = ((const float4*)(y + off))[t];
        const float4 pv = ((const float4*)(phi + off))[t];
        sA[4 * t + 0] = make_float2(yv.x, pv.x * iwv);
        sA[4 * t + 1] = make_float2(yv.y, pv.y * iwv);
        sA[4 * t + 2] = make_float2(yv.z, pv.z * iwv);
        sA[4 * t + 3] = make_float2(yv.w, pv.w * iwv);
        __syncthreads();
        float2* R = fft512<-1>(sA, sB, tw, t);
        float4* wp = (float4*)(S + off);
        for (int k = t; k < 256; k += 128)
            wp[k] = make_float4(R[2 * k].x, R[2 * k].y,
                                R[2 * k + 1].x, R[2 * k + 1].y);
        return;
    }
    const int bid = blockIdx.x - 6144;  // 0..126
    int img, row;
    if (bid < 100) {
        img = 12 + bid / 25;
        row = (bid % 25 - 12) & 511;
    } else {
        const int g = bid - 100;
        img = 16 + g / 9;
        row = ((g % 9) - 4) & 511;
    }
    float2* rp = S + (size_t)img * NPIX + (size_t)row * 512;
    for (int k = t; k < 512; k += 128) sA[k] = rp[k];
    __syncthreads();
    float2* R = fft512<-1>(sA, sB, tw, t);
    for (int k = t; k < 512; k += 128) rp[k] = R[k];
}

// ---------------------------------------------------------------------------
// Generic in-place row FFT, one block per row. float4 global I/O.
// ---------------------------------------------------------------------------
template<int DIR>
__global__ __launch_bounds__(128) void fft_rows(float2* __restrict__ D) {
    __shared__ float2 sA[512], sB[512], tw[384];
    const int t = threadIdx.x;
    fill_tw<DIR>(tw, t, 128);
    float2* rp = D + (size_t)blockIdx.x * 512;
    const float4* rp4 = (const float4*)rp;
    for (int k = t; k < 256; k += 128) {
        const float4 v = rp4[k];
        sA[2 * k]     = make_float2(v.x, v.y);
        sA[2 * k + 1] = make_float2(v.z, v.w);
    }
    __syncthreads();
    float2* R = fft512<DIR>(sA, sB, tw, t);
    float4* wp = (float4*)rp;
    for (int k = t; k < 256; k += 128)
        wp[k] = make_float4(R[2 * k].x, R[2 * k].y,
                            R[2 * k + 1].x, R[2 * k + 1].y);
}

__device__ __forceinline__ float2 get2(const float4 a, const float4 b, int q) {
    switch (q) {
        case 0:  return make_float2(a.x, a.y);
        case 1:  return make_float2(a.z, a.w);
        case 2:  return make_float2(b.x, b.y);
        default: return make_float2(b.z, b.w);
    }
}

// ---------------------------------------------------------------------------
// FUSED Wiener combine + inverse row-FFT (pass 1 of ifft2).
// Block = (row-pair rr in [0,257), pair in [0,6)); 256 threads = two
// 128-lane halves, half h owns output row rh (r0=rr, r1=(512-rr)&511).
// Each half computes num = Omega*(conj(Dk)*Fy + Fphi) for its row directly
// from global spectra (Hermitian unpack needs rows rh and ro=other row;
// negated-column reads are reverse-contiguous -> cache-served), packs the
// image pair as num0 + i*num1 into LDS, and runs the inverse FFT in place.
// Writes P rows directly (saves the 24MB P round-trip + one launch).
// Both halves execute fft512 in lockstep (identical barrier sequence);
// for rr=0/256 (self-paired rows) half 1 computes a duplicate and skips
// the store.
// ---------------------------------------------------------------------------
__global__ __launch_bounds__(256) void combine_ifft(const float2* __restrict__ S,
                                                    const float* __restrict__ w,
                                                    float2* __restrict__ P) {
    __shared__ float2 sA[2][512], sB[2][512], tw[384];
    const int t = threadIdx.x;
    const int h = t >> 7, tt = t & 127;
    const int rr = blockIdx.x;    // 0..256
    const int pair = blockIdx.y;  // 0..5
    const int r0 = rr, r1 = (512 - rr) & 511;
    const int rh = h ? r1 : r0;
    const int ro = h ? r0 : r1;
    fill_tw<1>(tw, t, 256);
    const int i0 = 2 * pair, i1 = 2 * pair + 1;
    const int b0 = i0 / 3, b1 = i1 / 3;
    const int ch0 = i0 % 3, ch1 = i1 % 3;
    const float iw0 = 1.0f / w[b0], iw1 = 1.0f / w[b1];
    const size_t rowh = (size_t)rh * 512, rowo = (size_t)ro * 512;
    const float4* Zv0 = (const float4*)(S + (size_t)i0 * NPIX + rowh);
    const float4* Zv1 = (const float4*)(S + (size_t)i1 * NPIX + rowh);
    const float2* Zn0 = S + (size_t)i0 * NPIX + rowo;
    const float2* Zn1 = S + (size_t)i1 * NPIX + rowo;
    const float4* K0 = (const float4*)(S + (size_t)(12 + b0) * NPIX + rowh);
    const float4* K1 = (const float4*)(S + (size_t)(12 + b1) * NPIX + rowh);
    const float4* G0 = (const float4*)(S + (size_t)(16 + ch0) * NPIX + rowh);
    const float4* G1 = (const float4*)(S + (size_t)(16 + ch1) * NPIX + rowh);

    const float4 za = Zv0[2 * tt], zb = Zv0[2 * tt + 1];
    const float4 ua = Zv1[2 * tt], ub = Zv1[2 * tt + 1];
    const float4 ka = K0[2 * tt],  kb = K0[2 * tt + 1];
    const float4 la = K1[2 * tt],  lb = K1[2 * tt + 1];
    const float4 ga = G0[2 * tt],  gb = G0[2 * tt + 1];
    const float4 ha = G1[2 * tt],  hb = G1[2 * tt + 1];
#pragma unroll
    for (int q = 0; q < 4; ++q) {
        const int c = 4 * tt + q;
        const int nc = (512 - c) & 511;
        float2 num[2];
#pragma unroll
        for (int e = 0; e < 2; ++e) {
            const float2 Zv = e ? get2(ua, ub, q) : get2(za, zb, q);
            const float2 Zn = e ? Zn1[nc] : Zn0[nc];
            const float2 K  = e ? get2(la, lb, q) : get2(ka, kb, q);
            const float dg  = (e ? get2(ha, hb, q).x : get2(ga, gb, q).x) *
                              (e ? iw1 : iw0);
            const float2 Zm = make_float2(Zn.x, -Zn.y);  // conj(Z(-u))
            const float2 Fy = make_float2(0.5f * (Zv.x + Zm.x),
                                          0.5f * (Zv.y + Zm.y));
            const float dx = Zv.x - Zm.x, dy = Zv.y - Zm.y;
            const float2 Fphi = make_float2(0.5f * dy, -0.5f * dx);
            const float kk = K.x * K.x + K.y * K.y;
            const float Om = 1.0f / (kk + dg);
            const float2 cf = make_float2(K.x * Fy.x + K.y * Fy.y,
                                          K.x * Fy.y - K.y * Fy.x);
            num[e] = make_float2(Om * (cf.x + Fphi.x), Om * (cf.y + Fphi.y));
        }
        sA[h][c] = make_float2(num[0].x - num[1].y, num[0].y + num[1].x);
    }
    __syncthreads();
    float2* R = fft512<1>(&sA[h][0], &sB[h][0], tw, tt);
    if (!(h == 1 && r1 == r0)) {
        float4* wp = (float4*)(P + (size_t)pair * NPIX + rowh);
        for (int k = tt; k < 256; k += 128)
            wp[k] = make_float4(R[2 * k].x, R[2 * k].y,
                                R[2 * k + 1].x, R[2 * k + 1].y);
    }
}

// ---------------------------------------------------------------------------
// Inverse pass 2 fused with real unpack: row FFT then Re->img 2p, Im->img
// 2p+1, scaled 1/N^2. float4 stores.
// ---------------------------------------------------------------------------
__global__ __launch_bounds__(128) void inv_fft_unpack(const float2* __restrict__ T,
                                                      float* __restrict__ out) {
    __shared__ float2 sA[512], sB[512], tw[384];
    const int t = threadIdx.x;
    const int pair = blockIdx.x >> 9, row = blockIdx.x & 511;
    fill_tw<1>(tw, t, 128);
    const float2* rp = T + (size_t)pair * NPIX + (size_t)row * 512;
    const float4* rp4 = (const float4*)rp;
    for (int k = t; k < 256; k += 128) {
        const float4 v = rp4[k];
        sA[2 * k]     = make_float2(v.x, v.y);
        sA[2 * k + 1] = make_float2(v.z, v.w);
    }
    __syncthreads();
    float2* R = fft512<1>(sA, sB, tw, t);
    const float sc = 1.0f / 262144.0f;
    float* o0 = out + (size_t)(2 * pair) * NPIX + (size_t)row * 512;
    float* o1 = o0 + NPIX;
    ((float4*)o0)[t] = make_float4(R[4 * t].x * sc, R[4 * t + 1].x * sc,
                                   R[4 * t + 2].x * sc, R[4 * t + 3].x * sc);
    ((float4*)o1)[t] = make_float4(R[4 * t].y * sc, R[4 * t + 1].y * sc,
                                   R[4 * t + 2].y * sc, R[4 * t + 3].y * sc);
}

// ---------------------------------------------------------------------------
// IN-PLACE 512x512 transpose per image (blockIdx.z): tile-pair swap.
// ---------------------------------------------------------------------------
__global__ __launch_bounds__(256) void transpose512_inplace(float2* __restrict__ D) {
    if (blockIdx.x > blockIdx.y) return;
    __shared__ float2 tA[32][33], tB[32][33];
    const size_t base = (size_t)blockIdx.z * NPIX;
    const int bi = blockIdx.x * 32, bj = blockIdx.y * 32;
    const int tx = threadIdx.x, ty = threadIdx.y;  // (32, 8)
    const bool diag = (bi == bj);
#pragma unroll
    for (int j = 0; j < 32; j += 8)
        tA[ty + j][tx] = D[base + (size_t)(bj + ty + j) * 512 + bi + tx];
    if (!diag) {
#pragma unroll
        for (int j = 0; j < 32; j += 8)
            tB[ty + j][tx] = D[base + (size_t)(bi + ty + j) * 512 + bj + tx];
    }
    __syncthreads();
#pragma unroll
    for (int j = 0; j < 32; j += 8)
        D[base + (size_t)(bi + ty + j) * 512 + bj + tx] = tA[tx][ty + j];
    if (!diag) {
#pragma unroll
        for (int j = 0; j < 32; j += 8)
            D[base + (size_t)(bj + ty + j) * 512 + bi + tx] = tB[tx][ty + j];
    }
}

// ---------------------------------------------------------------------------
// Out-of-place 512x512 transpose per image (blockIdx.z) — inverse path only.
// ---------------------------------------------------------------------------
__global__ __launch_bounds__(256) void transpose512(const float2* __restrict__ in,
                                                    float2* __restrict__ out) {
    __shared__ float2 tile[32][33];
    const size_t base = (size_t)blockIdx.z * NPIX;
    const int bx = blockIdx.x * 32, by = blockIdx.y * 32;
    const int tx = threadIdx.x, ty = threadIdx.y;  // (32, 8)
#pragma unroll
    for (int j = 0; j < 32; j += 8)
        tile[ty + j][tx] = in[base + (size_t)(by + ty + j) * 512 + bx + tx];
    __syncthreads();
#pragma unroll
    for (int j = 0; j < 32; j += 8)
        out[base + (size_t)(bx + ty + j) * 512 + by + tx] = tile[tx][ty + j];
}

// ---------------------------------------------------------------------------
// Sparse-input prep (parallel + branch-free, round-6 version).
// Blocks 0..9: pad+roll k into imgs 12..15. Blocks 10..12: per-channel
// summed autocorrelation of weights (13x13 zero-padded LDS stage -> no
// divergent conditionals) into imgs 16..18. Region pre-zeroed by memset.
// ---------------------------------------------------------------------------
__global__ __launch_bounds__(256) void prep_kg(const float* __restrict__ kin,
                                               const float* __restrict__ wts,
                                               float2* __restrict__ S) {
    const int bid = blockIdx.x, tid = threadIdx.x;
    if (bid < 10) {
        const int t = bid * 256 + tid;
        if (t < 2500) {
            const int b = t / 625, rem = t % 625;
            const int i = rem / 25, j = rem % 25;
            const int r = (i - 12) & 511, c = (j - 12) & 511;
            S[(size_t)(12 + b) * NPIX + (size_t)r * 512 + c] =
                make_float2(kin[t], 0.0f);
        }
        return;
    }
    const int ch = bid - 10;  // 0..2
    __shared__ float gp[24][13][13];
    __shared__ float part[243];
    float* gpf = &gp[0][0][0];
    for (int i = tid; i < 24 * 169; i += 256) gpf[i] = 0.0f;
    __syncthreads();
    for (int i = tid; i < 600; i += 256) {
        const int f = i / 25, rem = i % 25;
        const int x = rem / 5, yy = rem % 5;
        gp[f][x + 4][yy + 4] = wts[(size_t)(f * 3 + ch) * 25 + rem];
    }
    __syncthreads();
    if (tid < 243) {
        const int dpos = tid / 3, seg = tid % 3;
        const int di = dpos / 9 - 4, dj = dpos % 9 - 4;
        float acc = 0.0f;
        for (int f = seg * 8; f < seg * 8 + 8; ++f) {
#pragma unroll
            for (int x = 0; x < 5; ++x)
#pragma unroll
                for (int yy = 0; yy < 5; ++yy)
                    acc += gp[f][x + 4][yy + 4] *
                           gp[f][x + di + 4][yy + dj + 4];
        }
        part[tid] = acc;
    }
    __syncthreads();
    if (tid < 81) {
        const float a = part[tid * 3] + part[tid * 3 + 1] + part[tid * 3 + 2];
        const int di = tid / 9 - 4, dj = tid % 9 - 4;
        const int r = di & 511, c = dj & 511;
        S[(size_t)(16 + ch) * NPIX + (size_t)r * 512 + c] =
            make_float2(a, 0.0f);
    }
}

// ---------------------------------------------------------------------------
extern "C" void kernel_launch(void* const* d_in, const int* in_sizes, int n_in,
                              void* d_out, int out_size, void* d_ws, size_t ws_size,
                              hipStream_t stream) {
    const float* y   = (const float*)d_in[0];
    const float* k   = (const float*)d_in[1];
    const float* w   = (const float*)d_in[2];
    const float* phi = (const float*)d_in[3];
    const float* wts = (const float*)d_in[4];
    float* out = (float*)d_out;

    // workspace: S = 19 images (12 y/phi + 4 K + 3 G) + P = 6 images. 50 MB.
    const size_t needed = (size_t)25 * NPIX * sizeof(float2);
    if (ws_size < needed) return;  // clean incorrectness signal, never OOB
    float2* S = (float2*)d_ws;
    float2* P = S + (size_t)19 * NPIX;

    // zero only the sparse K/G region (imgs 12..18)
    hipMemsetAsync(S + (size_t)12 * NPIX, 0,
                   (size_t)7 * NPIX * sizeof(float2), stream);

    prep_kg<<<13, 256, 0, stream>>>(k, wts, S);
    fwd_fft_all<<<6271, 128, 0, stream>>>(y, phi, w, S);

    dim3 tb(32, 8);
    transpose512_inplace<<<dim3(16, 16, 19), tb, 0, stream>>>(S);
    fft_rows<-1><<<19 * 512, 128, 0, stream>>>(S);

    combine_ifft<<<dim3(257, 6), 256, 0, stream>>>(S, w, P);

    transpose512<<<dim3(16, 16, 6), tb, 0, stream>>>(P, S);  // S[0..5] free
    inv_fft_unpack<<<6 * 512, 128, 0, stream>>>(S, out);
}

// Round 10
// 148.679 us; speedup vs baseline: 1.3974x; 1.0724x over previous
//
#include <hip/hip_runtime.h>
#include <math.h>

#define PI_F 3.14159265358979323846f
#define NPIX 262144  // 512*512

__device__ __forceinline__ float2 cmul(float2 a, float2 b) {
    return make_float2(a.x * b.x - a.y * b.y, a.x * b.y + a.y * b.x);
}
__device__ __forceinline__ float2 cadd(float2 a, float2 b) {
    return make_float2(a.x + b.x, a.y + b.y);
}
__device__ __forceinline__ float2 csub(float2 a, float2 b) {
    return make_float2(a.x - b.x, a.y - b.y);
}

// twiddle table: tw[m] = exp(DIR * 2*pi*i * m / 512), m in [0,384).
// Exact multiples of 2pi/512, |ang| < 1.5pi -> native __sinf/__cosf accurate.
template<int DIR>
__device__ __forceinline__ void fill_tw(float2* tw, int t, int stride) {
    for (int m = t; m < 384; m += stride) {
        const float ang = (2.0f * PI_F / 512.0f) * (float)m;
        const float s = __sinf(ang), c = __cosf(ang);
        tw[m] = make_float2(c, (DIR > 0) ? s : -s);
    }
}

// ---------------------------------------------------------------------------
// 512-pt Stockham FFT, two-buffer ping-pong (5 barriers). 128 worker lanes.
// Caller syncs after filling sA+tw. Returns result pointer (= sB).
// ---------------------------------------------------------------------------
template<int DIR>
__device__ __forceinline__ float2* fft512(float2* sA, float2* sB,
                                          const float2* tw, int t) {
    float2* X = sA;
    float2* Y = sB;
    int Ns = 1;
#pragma unroll
    for (int s = 0; s < 4; ++s) {  // Ns = 1, 4, 16, 64
        const int jm = t & (Ns - 1);
        const int jd = t - jm;
        float2 v0 = X[t], v1 = X[t + 128], v2 = X[t + 256], v3 = X[t + 384];
        const int m1 = jm * (128 / Ns);
        v1 = cmul(tw[m1], v1);
        v2 = cmul(tw[2 * m1], v2);
        v3 = cmul(tw[3 * m1], v3);
        const float2 t0 = cadd(v0, v2), t1 = csub(v0, v2);
        const float2 t2 = cadd(v1, v3), t3 = csub(v1, v3);
        const float2 t3i = (DIR > 0) ? make_float2(-t3.y, t3.x)
                                     : make_float2(t3.y, -t3.x);
        const int od = (jd << 2) + jm;  // expand(j, Ns, 4)
        Y[od]          = cadd(t0, t2);
        Y[od + Ns]     = cadd(t1, t3i);
        Y[od + 2 * Ns] = csub(t0, t2);
        Y[od + 3 * Ns] = csub(t1, t3i);
        __syncthreads();
        float2* tmp = X; X = Y; Y = tmp;
        Ns <<= 2;
    }
#pragma unroll
    for (int q = 0; q < 2; ++q) {  // final radix-2, Ns = 256
        const int j = t + q * 128;
        const float2 a = X[j], b = X[j + 256];
        const float2 tt = cmul(tw[j], b);
        Y[j]       = cadd(a, tt);
        Y[j + 256] = csub(a, tt);
    }
    __syncthreads();
    return Y;
}

// ---------------------------------------------------------------------------
// 512-pt Stockham FFT, SINGLE-buffer in-place variant (read-barrier-write,
// 2 barriers/stage). Same index math as fft512; used by the column-FFT
// kernels where 8 concurrent columns must fit in static LDS. Result in X.
// ---------------------------------------------------------------------------
template<int DIR>
__device__ __forceinline__ void fft512_1b(float2* X, const float2* tw, int t) {
    int Ns = 1;
#pragma unroll
    for (int s = 0; s < 4; ++s) {  // Ns = 1, 4, 16, 64
        const int jm = t & (Ns - 1);
        const int jd = t - jm;
        float2 v0 = X[t], v1 = X[t + 128], v2 = X[t + 256], v3 = X[t + 384];
        __syncthreads();  // all reads done before in-place writes
        const int m1 = jm * (128 / Ns);
        v1 = cmul(tw[m1], v1);
        v2 = cmul(tw[2 * m1], v2);
        v3 = cmul(tw[3 * m1], v3);
        const float2 t0 = cadd(v0, v2), t1 = csub(v0, v2);
        const float2 t2 = cadd(v1, v3), t3 = csub(v1, v3);
        const float2 t3i = (DIR > 0) ? make_float2(-t3.y, t3.x)
                                     : make_float2(t3.y, -t3.x);
        const int od = (jd << 2) + jm;
        X[od]          = cadd(t0, t2);
        X[od + Ns]     = cadd(t1, t3i);
        X[od + 2 * Ns] = csub(t0, t2);
        X[od + 3 * Ns] = csub(t1, t3i);
        __syncthreads();
        Ns <<= 2;
    }
    // final radix-2 (j = t and t+128; pairs (j, j+256)), in place
    const float2 a0 = X[t],       b0 = X[t + 256];
    const float2 a1 = X[t + 128], b1 = X[t + 384];
    __syncthreads();
    const float2 u0 = cmul(tw[t], b0);
    const float2 u1 = cmul(tw[t + 128], b1);
    X[t]       = cadd(a0, u0);
    X[t + 256] = csub(a0, u0);
    X[t + 128] = cadd(a1, u1);
    X[t + 384] = csub(a1, u1);
    __syncthreads();
}

// ---------------------------------------------------------------------------
// Forward pass 1, merged: blocks 0..6143 = row FFT of (y + i*phi/w[b]) for
// the 12 y/phi images (fused packing, float4 loads); blocks 6144..6270 =
// in-place row FFT of the 127 nonzero K/G rows (prep_kg output).
// ---------------------------------------------------------------------------
__global__ __launch_bounds__(128) void fwd_fft_all(const float* __restrict__ y,
                                                   const float* __restrict__ phi,
                                                   const float* __restrict__ w,
                                                   float2* __restrict__ S) {
    __shared__ float2 sA[512], sB[512], tw[384];
    const int t = threadIdx.x;
    fill_tw<-1>(tw, t, 128);
    if (blockIdx.x < 6144) {
        const int img = blockIdx.x >> 9, row = blockIdx.x & 511;
        const size_t off = (size_t)img * NPIX + (size_t)row * 512;
        const float iwv = 1.0f / w[img / 3];
        const float4 yv = ((const float4*)(y + off))[t];
        const float4 pv = ((const float4*)(phi + off))[t];
        sA[4 * t + 0] = make_float2(yv.x, pv.x * iwv);
        sA[4 * t + 1] = make_float2(yv.y, pv.y * iwv);
        sA[4 * t + 2] = make_float2(yv.z, pv.z * iwv);
        sA[4 * t + 3] = make_float2(yv.w, pv.w * iwv);
        __syncthreads();
        float2* R = fft512<-1>(sA, sB, tw, t);
        float4* wp = (float4*)(S + off);
        for (int k = t; k < 256; k += 128)
            wp[k] = make_float4(R[2 * k].x, R[2 * k].y,
                                R[2 * k + 1].x, R[2 * k + 1].y);
        return;
    }
    const int bid = blockIdx.x - 6144;  // 0..126
    int img, row;
    if (bid < 100) {
        img = 12 + bid / 25;
        row = (bid % 25 - 12) & 511;
    } else {
        const int g = bid - 100;
        img = 16 + g / 9;
        row = ((g % 9) - 4) & 511;
    }
    float2* rp = S + (size_t)img * NPIX + (size_t)row * 512;
    for (int k = t; k < 512; k += 128) sA[k] = rp[k];
    __syncthreads();
    float2* R = fft512<-1>(sA, sB, tw, t);
    for (int k = t; k < 512; k += 128) rp[k] = R[k];
}

// ---------------------------------------------------------------------------
// FUSED transpose + column FFT (replaces transpose pass + row-FFT pass).
// Block = (img, column-tile of 8): reads the 8-column strip via 64B row
// segments (float4 = 2 complex), FFTs each column in LDS (single-buffer,
// per-column stride 513 -> <=2-way bank aliasing), writes each column's
// result as a CONTIGUOUS row of the output -> transpose for free.
// OUT-OF-PLACE (in != out) to avoid cross-block read/write races.
// 1024 threads = 8 columns x 128 lanes; ~36KB LDS -> 2 blocks/CU.
// ---------------------------------------------------------------------------
template<int DIR>
__global__ __launch_bounds__(1024) void col_fft(const float2* __restrict__ in,
                                                float2* __restrict__ outp) {
    __shared__ float2 sX[8 * 513], tw[384];
    const int t = threadIdx.x;
    const int img = blockIdx.x >> 6;
    const int u0 = (blockIdx.x & 63) << 3;
    fill_tw<DIR>(tw, t, 1024);
    const float2* ip = in + (size_t)img * NPIX + u0;
    for (int f = t; f < 2048; f += 1024) {
        const int row = f >> 2, seg = f & 3;
        const float4 v = *(const float4*)(ip + (size_t)row * 512 + seg * 2);
        sX[(seg * 2)     * 513 + row] = make_float2(v.x, v.y);
        sX[(seg * 2 + 1) * 513 + row] = make_float2(v.z, v.w);
    }
    __syncthreads();
    const int c = t >> 7, tt = t & 127;
    float2* X = sX + c * 513;
    fft512_1b<DIR>(X, tw, tt);
    float4* wp = (float4*)(outp + (size_t)img * NPIX + (size_t)(u0 + c) * 512);
    for (int k = tt; k < 256; k += 128)
        wp[k] = make_float4(X[2 * k].x, X[2 * k].y,
                            X[2 * k + 1].x, X[2 * k + 1].y);
}

__device__ __forceinline__ float2 get2(const float4 a, const float4 b, int q) {
    switch (q) {
        case 0:  return make_float2(a.x, a.y);
        case 1:  return make_float2(a.z, a.w);
        case 2:  return make_float2(b.x, b.y);
        default: return make_float2(b.z, b.w);
    }
}

// ---------------------------------------------------------------------------
// FUSED Wiener combine + inverse row-FFT (pass 1 of ifft2).
// Block = (row-pair rr in [0,257), pair in [0,6)); 256 threads = two
// 128-lane halves, half h owns output row rh (r0=rr, r1=(512-rr)&511).
// Reads transposed spectra from T, writes P rows directly.
// ---------------------------------------------------------------------------
__global__ __launch_bounds__(256) void combine_ifft(const float2* __restrict__ T,
                                                    const float* __restrict__ w,
                                                    float2* __restrict__ P) {
    __shared__ float2 sA[2][512], sB[2][512], tw[384];
    const int t = threadIdx.x;
    const int h = t >> 7, tt = t & 127;
    const int rr = blockIdx.x;    // 0..256
    const int pair = blockIdx.y;  // 0..5
    const int r0 = rr, r1 = (512 - rr) & 511;
    const int rh = h ? r1 : r0;
    const int ro = h ? r0 : r1;
    fill_tw<1>(tw, t, 256);
    const int i0 = 2 * pair, i1 = 2 * pair + 1;
    const int b0 = i0 / 3, b1 = i1 / 3;
    const int ch0 = i0 % 3, ch1 = i1 % 3;
    const float iw0 = 1.0f / w[b0], iw1 = 1.0f / w[b1];
    const size_t rowh = (size_t)rh * 512, rowo = (size_t)ro * 512;
    const float4* Zv0 = (const float4*)(T + (size_t)i0 * NPIX + rowh);
    const float4* Zv1 = (const float4*)(T + (size_t)i1 * NPIX + rowh);
    const float2* Zn0 = T + (size_t)i0 * NPIX + rowo;
    const float2* Zn1 = T + (size_t)i1 * NPIX + rowo;
    const float4* K0 = (const float4*)(T + (size_t)(12 + b0) * NPIX + rowh);
    const float4* K1 = (const float4*)(T + (size_t)(12 + b1) * NPIX + rowh);
    const float4* G0 = (const float4*)(T + (size_t)(16 + ch0) * NPIX + rowh);
    const float4* G1 = (const float4*)(T + (size_t)(16 + ch1) * NPIX + rowh);

    const float4 za = Zv0[2 * tt], zb = Zv0[2 * tt + 1];
    const float4 ua = Zv1[2 * tt], ub = Zv1[2 * tt + 1];
    const float4 ka = K0[2 * tt],  kb = K0[2 * tt + 1];
    const float4 la = K1[2 * tt],  lb = K1[2 * tt + 1];
    const float4 ga = G0[2 * tt],  gb = G0[2 * tt + 1];
    const float4 ha = G1[2 * tt],  hb = G1[2 * tt + 1];
#pragma unroll
    for (int q = 0; q < 4; ++q) {
        const int c = 4 * tt + q;
        const int nc = (512 - c) & 511;
        float2 num[2];
#pragma unroll
        for (int e = 0; e < 2; ++e) {
            const float2 Zv = e ? get2(ua, ub, q) : get2(za, zb, q);
            const float2 Zn = e ? Zn1[nc] : Zn0[nc];
            const float2 K  = e ? get2(la, lb, q) : get2(ka, kb, q);
            const float dg  = (e ? get2(ha, hb, q).x : get2(ga, gb, q).x) *
                              (e ? iw1 : iw0);
            const float2 Zm = make_float2(Zn.x, -Zn.y);  // conj(Z(-u))
            const float2 Fy = make_float2(0.5f * (Zv.x + Zm.x),
                                          0.5f * (Zv.y + Zm.y));
            const float dx = Zv.x - Zm.x, dy = Zv.y - Zm.y;
            const float2 Fphi = make_float2(0.5f * dy, -0.5f * dx);
            const float kk = K.x * K.x + K.y * K.y;
            const float Om = 1.0f / (kk + dg);
            const float2 cf = make_float2(K.x * Fy.x + K.y * Fy.y,
                                          K.x * Fy.y - K.y * Fy.x);
            num[e] = make_float2(Om * (cf.x + Fphi.x), Om * (cf.y + Fphi.y));
        }
        sA[h][c] = make_float2(num[0].x - num[1].y, num[0].y + num[1].x);
    }
    __syncthreads();
    float2* R = fft512<1>(&sA[h][0], &sB[h][0], tw, tt);
    if (!(h == 1 && r1 == r0)) {
        float4* wp = (float4*)(P + (size_t)pair * NPIX + rowh);
        for (int k = tt; k < 256; k += 128)
            wp[k] = make_float4(R[2 * k].x, R[2 * k].y,
                                R[2 * k + 1].x, R[2 * k + 1].y);
    }
}

// ---------------------------------------------------------------------------
// FUSED transpose + inverse column FFT + real unpack (replaces transpose
// pass + inv_fft_unpack). Same structure as col_fft; column c (spatial row
// s0+c) is IFFT'd along the stride dim then written as two contiguous REAL
// output rows: Re -> img 2*pair, Im -> img 2*pair+1, scaled 1/N^2.
// ---------------------------------------------------------------------------
__global__ __launch_bounds__(1024) void col_ifft_unpack(const float2* __restrict__ P,
                                                        float* __restrict__ out) {
    __shared__ float2 sX[8 * 513], tw[384];
    const int t = threadIdx.x;
    const int pair = blockIdx.x >> 6;
    const int s0 = (blockIdx.x & 63) << 3;
    fill_tw<1>(tw, t, 1024);
    const float2* ip = P + (size_t)pair * NPIX + s0;
    for (int f = t; f < 2048; f += 1024) {
        const int row = f >> 2, seg = f & 3;
        const float4 v = *(const float4*)(ip + (size_t)row * 512 + seg * 2);
        sX[(seg * 2)     * 513 + row] = make_float2(v.x, v.y);
        sX[(seg * 2 + 1) * 513 + row] = make_float2(v.z, v.w);
    }
    __syncthreads();
    const int c = t >> 7, tt = t & 127;
    float2* X = sX + c * 513;
    fft512_1b<1>(X, tw, tt);
    const float sc = 1.0f / 262144.0f;
    float* o0 = out + (size_t)(2 * pair) * NPIX + (size_t)(s0 + c) * 512;
    float* o1 = o0 + NPIX;
    ((float4*)o0)[tt] = make_float4(X[4 * tt].x * sc, X[4 * tt + 1].x * sc,
                                    X[4 * tt + 2].x * sc, X[4 * tt + 3].x * sc);
    ((float4*)o1)[tt] = make_float4(X[4 * tt].y * sc, X[4 * tt + 1].y * sc,
                                    X[4 * tt + 2].y * sc, X[4 * tt + 3].y * sc);
}

// ---------------------------------------------------------------------------
// Sparse-input prep (parallel + branch-free). Blocks 0..9: pad+roll k into
// imgs 12..15. Blocks 10..12: per-channel summed autocorrelation of weights
// (13x13 zero-padded LDS stage) into imgs 16..18. Region pre-zeroed.
// ---------------------------------------------------------------------------
__global__ __launch_bounds__(256) void prep_kg(const float* __restrict__ kin,
                                               const float* __restrict__ wts,
                                               float2* __restrict__ S) {
    const int bid = blockIdx.x, tid = threadIdx.x;
    if (bid < 10) {
        const int t = bid * 256 + tid;
        if (t < 2500) {
            const int b = t / 625, rem = t % 625;
            const int i = rem / 25, j = rem % 25;
            const int r = (i - 12) & 511, c = (j - 12) & 511;
            S[(size_t)(12 + b) * NPIX + (size_t)r * 512 + c] =
                make_float2(kin[t], 0.0f);
        }
        return;
    }
    const int ch = bid - 10;  // 0..2
    __shared__ float gp[24][13][13];
    __shared__ float part[243];
    float* gpf = &gp[0][0][0];
    for (int i = tid; i < 24 * 169; i += 256) gpf[i] = 0.0f;
    __syncthreads();
    for (int i = tid; i < 600; i += 256) {
        const int f = i / 25, rem = i % 25;
        const int x = rem / 5, yy = rem % 5;
        gp[f][x + 4][yy + 4] = wts[(size_t)(f * 3 + ch) * 25 + rem];
    }
    __syncthreads();
    if (tid < 243) {
        const int dpos = tid / 3, seg = tid % 3;
        const int di = dpos / 9 - 4, dj = dpos % 9 - 4;
        float acc = 0.0f;
        for (int f = seg * 8; f < seg * 8 + 8; ++f) {
#pragma unroll
            for (int x = 0; x < 5; ++x)
#pragma unroll
                for (int yy = 0; yy < 5; ++yy)
                    acc += gp[f][x + 4][yy + 4] *
                           gp[f][x + di + 4][yy + dj + 4];
        }
        part[tid] = acc;
    }
    __syncthreads();
    if (tid < 81) {
        const float a = part[tid * 3] + part[tid * 3 + 1] + part[tid * 3 + 2];
        const int di = tid / 9 - 4, dj = tid % 9 - 4;
        const int r = di & 511, c = dj & 511;
        S[(size_t)(16 + ch) * NPIX + (size_t)r * 512 + c] =
            make_float2(a, 0.0f);
    }
}

// ---------------------------------------------------------------------------
extern "C" void kernel_launch(void* const* d_in, const int* in_sizes, int n_in,
                              void* d_out, int out_size, void* d_ws, size_t ws_size,
                              hipStream_t stream) {
    const float* y   = (const float*)d_in[0];
    const float* k   = (const float*)d_in[1];
    const float* w   = (const float*)d_in[2];
    const float* phi = (const float*)d_in[3];
    const float* wts = (const float*)d_in[4];
    float* out = (float*)d_out;

    // workspace: S = 19 imgs (pass-1) | T = 19 imgs (col-FFT out).
    // P (inverse pass-1 out, 6 imgs) reuses S[0..5] (S dead after col_fft).
    const size_t needed = (size_t)38 * NPIX * sizeof(float2);  // 76 MB
    if (ws_size < needed) return;  // clean incorrectness signal, never OOB
    float2* S = (float2*)d_ws;
    float2* T = S + (size_t)19 * NPIX;
    float2* P = S;

    // zero only the sparse K/G region (imgs 12..18 of S)
    hipMemsetAsync(S + (size_t)12 * NPIX, 0,
                   (size_t)7 * NPIX * sizeof(float2), stream);

    prep_kg<<<13, 256, 0, stream>>>(k, wts, S);
    fwd_fft_all<<<6271, 128, 0, stream>>>(y, phi, w, S);

    // fused transpose + column FFT: S -> T (transposed spectra)
    col_fft<-1><<<19 * 64, 1024, 0, stream>>>(S, T);

    // Wiener combine + inverse row-FFT: T -> P
    combine_ifft<<<dim3(257, 6), 256, 0, stream>>>(T, w, P);

    // fused transpose + inverse column FFT + real unpack: P -> out
    col_ifft_unpack<<<6 * 64, 1024, 0, stream>>>(P, out);
}

// Round 11
// 144.710 us; speedup vs baseline: 1.4357x; 1.0274x over previous
//
#include <hip/hip_runtime.h>
#include <math.h>

#define PI_F 3.14159265358979323846f
#define NPIX 262144  // 512*512

__device__ __forceinline__ float2 cmul(float2 a, float2 b) {
    return make_float2(a.x * b.x - a.y * b.y, a.x * b.y + a.y * b.x);
}
__device__ __forceinline__ float2 cadd(float2 a, float2 b) {
    return make_float2(a.x + b.x, a.y + b.y);
}
__device__ __forceinline__ float2 csub(float2 a, float2 b) {
    return make_float2(a.x - b.x, a.y - b.y);
}

// twiddle table: tw[m] = exp(DIR * 2*pi*i * m / 512), m in [0,384).
// Exact multiples of 2pi/512, |ang| < 1.5pi -> native __sinf/__cosf accurate.
template<int DIR>
__device__ __forceinline__ void fill_tw(float2* tw, int t, int stride) {
    for (int m = t; m < 384; m += stride) {
        const float ang = (2.0f * PI_F / 512.0f) * (float)m;
        const float s = __sinf(ang), c = __cosf(ang);
        tw[m] = make_float2(c, (DIR > 0) ? s : -s);
    }
}

// ---------------------------------------------------------------------------
// 512-pt Stockham FFT, two-buffer ping-pong (5 internal barriers).
// 128 worker lanes; caller syncs after filling sA+tw. Result pointer = sB.
// Works on strided column views too (callers pass sA/sB bases 513 apart).
// ---------------------------------------------------------------------------
template<int DIR>
__device__ __forceinline__ float2* fft512(float2* sA, float2* sB,
                                          const float2* tw, int t) {
    float2* X = sA;
    float2* Y = sB;
    int Ns = 1;
#pragma unroll
    for (int s = 0; s < 4; ++s) {  // Ns = 1, 4, 16, 64
        const int jm = t & (Ns - 1);
        const int jd = t - jm;
        float2 v0 = X[t], v1 = X[t + 128], v2 = X[t + 256], v3 = X[t + 384];
        const int m1 = jm * (128 / Ns);
        v1 = cmul(tw[m1], v1);
        v2 = cmul(tw[2 * m1], v2);
        v3 = cmul(tw[3 * m1], v3);
        const float2 t0 = cadd(v0, v2), t1 = csub(v0, v2);
        const float2 t2 = cadd(v1, v3), t3 = csub(v1, v3);
        const float2 t3i = (DIR > 0) ? make_float2(-t3.y, t3.x)
                                     : make_float2(t3.y, -t3.x);
        const int od = (jd << 2) + jm;  // expand(j, Ns, 4)
        Y[od]          = cadd(t0, t2);
        Y[od + Ns]     = cadd(t1, t3i);
        Y[od + 2 * Ns] = csub(t0, t2);
        Y[od + 3 * Ns] = csub(t1, t3i);
        __syncthreads();
        float2* tmp = X; X = Y; Y = tmp;
        Ns <<= 2;
    }
#pragma unroll
    for (int q = 0; q < 2; ++q) {  // final radix-2, Ns = 256
        const int j = t + q * 128;
        const float2 a = X[j], b = X[j + 256];
        const float2 tt = cmul(tw[j], b);
        Y[j]       = cadd(a, tt);
        Y[j + 256] = csub(a, tt);
    }
    __syncthreads();
    return Y;
}

// ---------------------------------------------------------------------------
// Forward pass 1, merged: blocks 0..6143 = row FFT of (y + i*phi/w[b]) for
// the 12 y/phi images (fused packing, float4 loads); blocks 6144..6270 =
// in-place row FFT of the 127 nonzero K/G rows (prep_kg output).
// ---------------------------------------------------------------------------
__global__ __launch_bounds__(128) void fwd_fft_all(const float* __restrict__ y,
                                                   const float* __restrict__ phi,
                                                   const float* __restrict__ w,
                                                   float2* __restrict__ S) {
    __shared__ float2 sA[512], sB[512], tw[384];
    const int t = threadIdx.x;
    fill_tw<-1>(tw, t, 128);
    if (blockIdx.x < 6144) {
        const int img = blockIdx.x >> 9, row = blockIdx.x & 511;
        const size_t off = (size_t)img * NPIX + (size_t)row * 512;
        const float iwv = 1.0f / w[img / 3];
        const float4 yv = ((const float4*)(y + off))[t];
        const float4 pv = ((const float4*)(phi + off))[t];
        sA[4 * t + 0] = make_float2(yv.x, pv.x * iwv);
        sA[4 * t + 1] = make_float2(yv.y, pv.y * iwv);
        sA[4 * t + 2] = make_float2(yv.z, pv.z * iwv);
        sA[4 * t + 3] = make_float2(yv.w, pv.w * iwv);
        __syncthreads();
        float2* R = fft512<-1>(sA, sB, tw, t);
        float4* wp = (float4*)(S + off);
        for (int k = t; k < 256; k += 128)
            wp[k] = make_float4(R[2 * k].x, R[2 * k].y,
                                R[2 * k + 1].x, R[2 * k + 1].y);
        return;
    }
    const int bid = blockIdx.x - 6144;  // 0..126
    int img, row;
    if (bid < 100) {
        img = 12 + bid / 25;
        row = (bid % 25 - 12) & 511;
    } else {
        const int g = bid - 100;
        img = 16 + g / 9;
        row = ((g % 9) - 4) & 511;
    }
    float2* rp = S + (size_t)img * NPIX + (size_t)row * 512;
    for (int k = t; k < 512; k += 128) sA[k] = rp[k];
    __syncthreads();
    float2* R = fft512<-1>(sA, sB, tw, t);
    for (int k = t; k < 512; k += 128) rp[k] = R[k];
}

// ---------------------------------------------------------------------------
// FUSED transpose + column FFT. Block = (img, 8-column tile): reads the
// strip via 64B row segments, FFTs the 8 columns in LDS (ping-pong buffers,
// stride 513 -> <=2-way bank aliasing), writes each column's result as a
// CONTIGUOUS row of the output. OUT-OF-PLACE (cross-block safety).
// 1024 threads = 8 cols x 128 lanes; ~69KB LDS -> 2 blocks/CU (wave-capped).
// ---------------------------------------------------------------------------
template<int DIR>
__global__ __launch_bounds__(1024) void col_fft(const float2* __restrict__ in,
                                                float2* __restrict__ outp) {
    __shared__ float2 sX[8 * 513], sY[8 * 513], tw[384];
    const int t = threadIdx.x;
    const int img = blockIdx.x >> 6;
    const int u0 = (blockIdx.x & 63) << 3;
    fill_tw<DIR>(tw, t, 1024);
    const float2* ip = in + (size_t)img * NPIX + u0;
    for (int f = t; f < 2048; f += 1024) {
        const int row = f >> 2, seg = f & 3;
        const float4 v = *(const float4*)(ip + (size_t)row * 512 + seg * 2);
        sX[(seg * 2)     * 513 + row] = make_float2(v.x, v.y);
        sX[(seg * 2 + 1) * 513 + row] = make_float2(v.z, v.w);
    }
    __syncthreads();
    const int c = t >> 7, tt = t & 127;
    float2* R = fft512<DIR>(sX + c * 513, sY + c * 513, tw, tt);
    float4* wp = (float4*)(outp + (size_t)img * NPIX + (size_t)(u0 + c) * 512);
    for (int k = tt; k < 256; k += 128)
        wp[k] = make_float4(R[2 * k].x, R[2 * k].y,
                            R[2 * k + 1].x, R[2 * k + 1].y);
}

__device__ __forceinline__ float2 get2(const float4 a, const float4 b, int q) {
    switch (q) {
        case 0:  return make_float2(a.x, a.y);
        case 1:  return make_float2(a.z, a.w);
        case 2:  return make_float2(b.x, b.y);
        default: return make_float2(b.z, b.w);
    }
}

// ---------------------------------------------------------------------------
// FUSED Wiener combine + inverse row-FFT (pass 1 of ifft2).
// Block = (row-pair rr in [0,257), pair in [0,6)); two 128-lane halves, half
// h owns row rh (r0=rr, r1=(512-rr)&511). Each half loads ITS OWN Z rows
// coalesced and stages them in LDS; the conjugate-mirror row each half needs
// is exactly the OTHER half's staged row (zrow[1-h]) -> no global re-read,
// no reverse-gather (round-10 version re-read 24MB from global, reversed).
// Hermitian unpack, Wiener filter, pack pair as num0 + i*num1, inverse FFT.
// For rr=0/256 (self-paired) both halves stage the same row; h=1 skips store.
// ---------------------------------------------------------------------------
__global__ __launch_bounds__(256) void combine_ifft(const float2* __restrict__ T,
                                                    const float* __restrict__ w,
                                                    float2* __restrict__ P) {
    __shared__ float2 sA[2][512], sB[2][512], tw[384];
    __shared__ float2 zrow[2][2][512];  // [half][img-of-pair][v]
    const int t = threadIdx.x;
    const int h = t >> 7, tt = t & 127;
    const int rr = blockIdx.x;    // 0..256
    const int pair = blockIdx.y;  // 0..5
    const int r0 = rr, r1 = (512 - rr) & 511;
    const int rh = h ? r1 : r0;
    fill_tw<1>(tw, t, 256);
    const int i0 = 2 * pair, i1 = 2 * pair + 1;
    const int b0 = i0 / 3, b1 = i1 / 3;
    const int ch0 = i0 % 3, ch1 = i1 % 3;
    const float iw0 = 1.0f / w[b0], iw1 = 1.0f / w[b1];
    const size_t rowh = (size_t)rh * 512;
    const float4* Zv0 = (const float4*)(T + (size_t)i0 * NPIX + rowh);
    const float4* Zv1 = (const float4*)(T + (size_t)i1 * NPIX + rowh);
    const float4* K0 = (const float4*)(T + (size_t)(12 + b0) * NPIX + rowh);
    const float4* K1 = (const float4*)(T + (size_t)(12 + b1) * NPIX + rowh);
    const float4* G0 = (const float4*)(T + (size_t)(16 + ch0) * NPIX + rowh);
    const float4* G1 = (const float4*)(T + (size_t)(16 + ch1) * NPIX + rowh);

    const float4 za = Zv0[2 * tt], zb = Zv0[2 * tt + 1];
    const float4 ua = Zv1[2 * tt], ub = Zv1[2 * tt + 1];
    const float4 ka = K0[2 * tt],  kb = K0[2 * tt + 1];
    const float4 la = K1[2 * tt],  lb = K1[2 * tt + 1];
    const float4 ga = G0[2 * tt],  gb = G0[2 * tt + 1];
    const float4 ha = G1[2 * tt],  hb = G1[2 * tt + 1];
    // stage own rows for the other half's Hermitian mirror
    zrow[h][0][4 * tt + 0] = make_float2(za.x, za.y);
    zrow[h][0][4 * tt + 1] = make_float2(za.z, za.w);
    zrow[h][0][4 * tt + 2] = make_float2(zb.x, zb.y);
    zrow[h][0][4 * tt + 3] = make_float2(zb.z, zb.w);
    zrow[h][1][4 * tt + 0] = make_float2(ua.x, ua.y);
    zrow[h][1][4 * tt + 1] = make_float2(ua.z, ua.w);
    zrow[h][1][4 * tt + 2] = make_float2(ub.x, ub.y);
    zrow[h][1][4 * tt + 3] = make_float2(ub.z, ub.w);
    __syncthreads();
    const float2* Zm0 = zrow[1 - h][0];
    const float2* Zm1 = zrow[1 - h][1];
#pragma unroll
    for (int q = 0; q < 4; ++q) {
        const int c = 4 * tt + q;
        const int nc = (512 - c) & 511;
        float2 num[2];
#pragma unroll
        for (int e = 0; e < 2; ++e) {
            const float2 Zv = e ? get2(ua, ub, q) : get2(za, zb, q);
            const float2 Zn = e ? Zm1[nc] : Zm0[nc];
            const float2 K  = e ? get2(la, lb, q) : get2(ka, kb, q);
            const float dg  = (e ? get2(ha, hb, q).x : get2(ga, gb, q).x) *
                              (e ? iw1 : iw0);
            const float2 Zm = make_float2(Zn.x, -Zn.y);  // conj(Z(-u))
            const float2 Fy = make_float2(0.5f * (Zv.x + Zm.x),
                                          0.5f * (Zv.y + Zm.y));
            const float dx = Zv.x - Zm.x, dy = Zv.y - Zm.y;
            const float2 Fphi = make_float2(0.5f * dy, -0.5f * dx);
            const float kk = K.x * K.x + K.y * K.y;
            const float Om = 1.0f / (kk + dg);
            const float2 cf = make_float2(K.x * Fy.x + K.y * Fy.y,
                                          K.x * Fy.y - K.y * Fy.x);
            num[e] = make_float2(Om * (cf.x + Fphi.x), Om * (cf.y + Fphi.y));
        }
        sA[h][c] = make_float2(num[0].x - num[1].y, num[0].y + num[1].x);
    }
    __syncthreads();
    float2* R = fft512<1>(&sA[h][0], &sB[h][0], tw, tt);
    if (!(h == 1 && r1 == r0)) {
        float4* wp = (float4*)(P + (size_t)pair * NPIX + rowh);
        for (int k = tt; k < 256; k += 128)
            wp[k] = make_float4(R[2 * k].x, R[2 * k].y,
                                R[2 * k + 1].x, R[2 * k + 1].y);
    }
}

// ---------------------------------------------------------------------------
// FUSED transpose + inverse column FFT + real unpack. Same structure as
// col_fft; column c (spatial row s0+c) is IFFT'd then written as two
// contiguous REAL output rows: Re -> img 2*pair, Im -> img 2*pair+1, 1/N^2.
// ---------------------------------------------------------------------------
__global__ __launch_bounds__(1024) void col_ifft_unpack(const float2* __restrict__ P,
                                                        float* __restrict__ out) {
    __shared__ float2 sX[8 * 513], sY[8 * 513], tw[384];
    const int t = threadIdx.x;
    const int pair = blockIdx.x >> 6;
    const int s0 = (blockIdx.x & 63) << 3;
    fill_tw<1>(tw, t, 1024);
    const float2* ip = P + (size_t)pair * NPIX + s0;
    for (int f = t; f < 2048; f += 1024) {
        const int row = f >> 2, seg = f & 3;
        const float4 v = *(const float4*)(ip + (size_t)row * 512 + seg * 2);
        sX[(seg * 2)     * 513 + row] = make_float2(v.x, v.y);
        sX[(seg * 2 + 1) * 513 + row] = make_float2(v.z, v.w);
    }
    __syncthreads();
    const int c = t >> 7, tt = t & 127;
    float2* R = fft512<1>(sX + c * 513, sY + c * 513, tw, tt);
    const float sc = 1.0f / 262144.0f;
    float* o0 = out + (size_t)(2 * pair) * NPIX + (size_t)(s0 + c) * 512;
    float* o1 = o0 + NPIX;
    ((float4*)o0)[tt] = make_float4(R[4 * tt].x * sc, R[4 * tt + 1].x * sc,
                                    R[4 * tt + 2].x * sc, R[4 * tt + 3].x * sc);
    ((float4*)o1)[tt] = make_float4(R[4 * tt].y * sc, R[4 * tt + 1].y * sc,
                                    R[4 * tt + 2].y * sc, R[4 * tt + 3].y * sc);
}

// ---------------------------------------------------------------------------
// Sparse-input prep (parallel + branch-free). Blocks 0..9: pad+roll k into
// imgs 12..15. Blocks 10..12: per-channel summed autocorrelation of weights
// (13x13 zero-padded LDS stage) into imgs 16..18. Region pre-zeroed.
// ---------------------------------------------------------------------------
__global__ __launch_bounds__(256) void prep_kg(const float* __restrict__ kin,
                                               const float* __restrict__ wts,
                                               float2* __restrict__ S) {
    const int bid = blockIdx.x, tid = threadIdx.x;
    if (bid < 10) {
        const int t = bid * 256 + tid;
        if (t < 2500) {
            const int b = t / 625, rem = t % 625;
            const int i = rem / 25, j = rem % 25;
            const int r = (i - 12) & 511, c = (j - 12) & 511;
            S[(size_t)(12 + b) * NPIX + (size_t)r * 512 + c] =
                make_float2(kin[t], 0.0f);
        }
        return;
    }
    const int ch = bid - 10;  // 0..2
    __shared__ float gp[24][13][13];
    __shared__ float part[243];
    float* gpf = &gp[0][0][0];
    for (int i = tid; i < 24 * 169; i += 256) gpf[i] = 0.0f;
    __syncthreads();
    for (int i = tid; i < 600; i += 256) {
        const int f = i / 25, rem = i % 25;
        const int x = rem / 5, yy = rem % 5;
        gp[f][x + 4][yy + 4] = wts[(size_t)(f * 3 + ch) * 25 + rem];
    }
    __syncthreads();
    if (tid < 243) {
        const int dpos = tid / 3, seg = tid % 3;
        const int di = dpos / 9 - 4, dj = dpos % 9 - 4;
        float acc = 0.0f;
        for (int f = seg * 8; f < seg * 8 + 8; ++f) {
#pragma unroll
            for (int x = 0; x < 5; ++x)
#pragma unroll
                for (int yy = 0; yy < 5; ++yy)
                    acc += gp[f][x + 4][yy + 4] *
                           gp[f][x + di + 4][yy + dj + 4];
        }
        part[tid] = acc;
    }
    __syncthreads();
    if (tid < 81) {
        const float a = part[tid * 3] + part[tid * 3 + 1] + part[tid * 3 + 2];
        const int di = tid / 9 - 4, dj = tid % 9 - 4;
        const int r = di & 511, c = dj & 511;
        S[(size_t)(16 + ch) * NPIX + (size_t)r * 512 + c] =
            make_float2(a, 0.0f);
    }
}

// ---------------------------------------------------------------------------
extern "C" void kernel_launch(void* const* d_in, const int* in_sizes, int n_in,
                              void* d_out, int out_size, void* d_ws, size_t ws_size,
                              hipStream_t stream) {
    const float* y   = (const float*)d_in[0];
    const float* k   = (const float*)d_in[1];
    const float* w   = (const float*)d_in[2];
    const float* phi = (const float*)d_in[3];
    const float* wts = (const float*)d_in[4];
    float* out = (float*)d_out;

    // workspace: S = 19 imgs (pass-1) | T = 19 imgs (col-FFT out).
    // P (inverse pass-1 out, 6 imgs) reuses S[0..5] (S dead after col_fft).
    const size_t needed = (size_t)38 * NPIX * sizeof(float2);  // 76 MB
    if (ws_size < needed) return;  // clean incorrectness signal, never OOB
    float2* S = (float2*)d_ws;
    float2* T = S + (size_t)19 * NPIX;
    float2* P = S;

    // zero only the sparse K/G region (imgs 12..18 of S)
    hipMemsetAsync(S + (size_t)12 * NPIX, 0,
                   (size_t)7 * NPIX * sizeof(float2), stream);

    prep_kg<<<13, 256, 0, stream>>>(k, wts, S);
    fwd_fft_all<<<6271, 128, 0, stream>>>(y, phi, w, S);

    // fused transpose + column FFT: S -> T (transposed spectra)
    col_fft<-1><<<19 * 64, 1024, 0, stream>>>(S, T);

    // Wiener combine + inverse row-FFT: T -> P (mirror rows shared via LDS)
    combine_ifft<<<dim3(257, 6), 256, 0, stream>>>(T, w, P);

    // fused transpose + inverse column FFT + real unpack: P -> out
    col_ifft_unpack<<<6 * 64, 1024, 0, stream>>>(P, out);
}

// Round 12
// 138.888 us; speedup vs baseline: 1.4959x; 1.0419x over previous
//
#include <hip/hip_runtime.h>
#include <math.h>

#define PI_F 3.14159265358979323846f
#define NPIX 262144  // 512*512

__device__ __forceinline__ float2 cmul(float2 a, float2 b) {
    return make_float2(a.x * b.x - a.y * b.y, a.x * b.y + a.y * b.x);
}
__device__ __forceinline__ float2 cadd(float2 a, float2 b) {
    return make_float2(a.x + b.x, a.y + b.y);
}
__device__ __forceinline__ float2 csub(float2 a, float2 b) {
    return make_float2(a.x - b.x, a.y - b.y);
}

// twiddle table: tw[m] = exp(DIR * 2*pi*i * m / 512), m in [0,384).
// Exact multiples of 2pi/512, |ang| < 1.5pi -> native __sinf/__cosf accurate.
template<int DIR>
__device__ __forceinline__ void fill_tw(float2* tw, int t, int stride) {
    for (int m = t; m < 384; m += stride) {
        const float ang = (2.0f * PI_F / 512.0f) * (float)m;
        const float s = __sinf(ang), c = __cosf(ang);
        tw[m] = make_float2(c, (DIR > 0) ? s : -s);
    }
}

// ---------------------------------------------------------------------------
// 512-pt Stockham FFT, two-buffer ping-pong (5 internal barriers).
// 128 worker lanes; caller syncs after filling sA+tw. Result pointer = sB.
// Works on strided column views (callers pass sA/sB bases 513 apart).
// ---------------------------------------------------------------------------
template<int DIR>
__device__ __forceinline__ float2* fft512(float2* sA, float2* sB,
                                          const float2* tw, int t) {
    float2* X = sA;
    float2* Y = sB;
    int Ns = 1;
#pragma unroll
    for (int s = 0; s < 4; ++s) {  // Ns = 1, 4, 16, 64
        const int jm = t & (Ns - 1);
        const int jd = t - jm;
        float2 v0 = X[t], v1 = X[t + 128], v2 = X[t + 256], v3 = X[t + 384];
        const int m1 = jm * (128 / Ns);
        v1 = cmul(tw[m1], v1);
        v2 = cmul(tw[2 * m1], v2);
        v3 = cmul(tw[3 * m1], v3);
        const float2 t0 = cadd(v0, v2), t1 = csub(v0, v2);
        const float2 t2 = cadd(v1, v3), t3 = csub(v1, v3);
        const float2 t3i = (DIR > 0) ? make_float2(-t3.y, t3.x)
                                     : make_float2(t3.y, -t3.x);
        const int od = (jd << 2) + jm;  // expand(j, Ns, 4)
        Y[od]          = cadd(t0, t2);
        Y[od + Ns]     = cadd(t1, t3i);
        Y[od + 2 * Ns] = csub(t0, t2);
        Y[od + 3 * Ns] = csub(t1, t3i);
        __syncthreads();
        float2* tmp = X; X = Y; Y = tmp;
        Ns <<= 2;
    }
#pragma unroll
    for (int q = 0; q < 2; ++q) {  // final radix-2, Ns = 256
        const int j = t + q * 128;
        const float2 a = X[j], b = X[j + 256];
        const float2 tt = cmul(tw[j], b);
        Y[j]       = cadd(a, tt);
        Y[j + 256] = csub(a, tt);
    }
    __syncthreads();
    return Y;
}

// ---------------------------------------------------------------------------
// Per-channel summed autocorrelation of weights -> A3[3][81] (9x9 support).
// 3 blocks (one per channel); 13x13 zero-padded LDS stage -> branch-free MACs.
// ---------------------------------------------------------------------------
__global__ __launch_bounds__(256) void autocorr3(const float* __restrict__ wts,
                                                 float* __restrict__ A3) {
    const int ch = blockIdx.x, tid = threadIdx.x;
    __shared__ float gp[24][13][13];
    __shared__ float part[243];
    float* gpf = &gp[0][0][0];
    for (int i = tid; i < 24 * 169; i += 256) gpf[i] = 0.0f;
    __syncthreads();
    for (int i = tid; i < 600; i += 256) {
        const int f = i / 25, rem = i % 25;
        const int x = rem / 5, yy = rem % 5;
        gp[f][x + 4][yy + 4] = wts[(size_t)(f * 3 + ch) * 25 + rem];
    }
    __syncthreads();
    if (tid < 243) {
        const int dpos = tid / 3, seg = tid % 3;
        const int di = dpos / 9 - 4, dj = dpos % 9 - 4;
        float acc = 0.0f;
        for (int f = seg * 8; f < seg * 8 + 8; ++f) {
#pragma unroll
            for (int x = 0; x < 5; ++x)
#pragma unroll
                for (int yy = 0; yy < 5; ++yy)
                    acc += gp[f][x + 4][yy + 4] *
                           gp[f][x + di + 4][yy + dj + 4];
        }
        part[tid] = acc;
    }
    __syncthreads();
    if (tid < 81)
        A3[ch * 81 + tid] = part[tid * 3] + part[tid * 3 + 1] + part[tid * 3 + 2];
}

// ---------------------------------------------------------------------------
// Forward pass 1, merged. Blocks 0..6143: row FFT of (y + i*phi/w[b]), fused
// packing, float4 loads. Blocks 6144..6243: K rows — build the padded+rolled
// kernel row DIRECTLY in LDS from kin (no padded image in memory, no memset).
// Blocks 6244..6270: G rows — same from the A3 autocorr table.
// K/G blocks write their DENSE spectral row; all other rows of imgs 12..18
// are structural zeros that are never stored (col_fft synthesizes them).
// ---------------------------------------------------------------------------
__global__ __launch_bounds__(128) void fwd_fft_all(const float* __restrict__ y,
                                                   const float* __restrict__ phi,
                                                   const float* __restrict__ w,
                                                   const float* __restrict__ kin,
                                                   const float* __restrict__ A3,
                                                   float2* __restrict__ S) {
    __shared__ float2 sA[512], sB[512], tw[384];
    const int t = threadIdx.x;
    fill_tw<-1>(tw, t, 128);
    if (blockIdx.x < 6144) {
        const int img = blockIdx.x >> 9, row = blockIdx.x & 511;
        const size_t off = (size_t)img * NPIX + (size_t)row * 512;
        const float iwv = 1.0f / w[img / 3];
        const float4 yv = ((const float4*)(y + off))[t];
        const float4 pv = ((const float4*)(phi + off))[t];
        sA[4 * t + 0] = make_float2(yv.x, pv.x * iwv);
        sA[4 * t + 1] = make_float2(yv.y, pv.y * iwv);
        sA[4 * t + 2] = make_float2(yv.z, pv.z * iwv);
        sA[4 * t + 3] = make_float2(yv.w, pv.w * iwv);
        __syncthreads();
        float2* R = fft512<-1>(sA, sB, tw, t);
        float4* wp = (float4*)(S + off);
        for (int k = t; k < 256; k += 128)
            wp[k] = make_float4(R[2 * k].x, R[2 * k].y,
                                R[2 * k + 1].x, R[2 * k + 1].y);
        return;
    }
    const int bid = blockIdx.x - 6144;  // 0..126
    int img, row;
    // zero the row, then scatter the sparse entries
    for (int k = t; k < 512; k += 128) sA[k] = make_float2(0.0f, 0.0f);
    __syncthreads();
    if (bid < 100) {  // K: img 12+b, kernel row i (25 taps at cols (j-12)&511)
        const int b = bid / 25, i = bid % 25;
        img = 12 + b;
        row = (i - 12) & 511;
        if (t < 25)
            sA[(t - 12) & 511] = make_float2(kin[b * 625 + i * 25 + t], 0.0f);
    } else {          // G: img 16+ch, autocorr row di (9 taps at (dj-4)&511)
        const int g = bid - 100;
        const int ch = g / 9, di = g % 9;
        img = 16 + ch;
        row = (di - 4) & 511;
        if (t < 9)
            sA[(t - 4) & 511] = make_float2(A3[ch * 81 + di * 9 + t], 0.0f);
    }
    __syncthreads();
    float2* R = fft512<-1>(sA, sB, tw, t);
    float2* rp = S + (size_t)img * NPIX + (size_t)row * 512;
    for (int k = t; k < 512; k += 128) rp[k] = R[k];
}

// ---------------------------------------------------------------------------
// FUSED transpose + column FFT. Block = (img, 8-column tile): reads the
// strip via 64B row segments, FFTs the 8 columns in LDS (ping-pong buffers,
// stride 513 -> <=2-way bank aliasing), writes each column's result as a
// CONTIGUOUS row of the output. For imgs >= 12 (K/G), rows outside the
// sparse support were never stored -> synthesize zeros instead of loading
// (saves ~95% of K/G reads and removes the memset dependency entirely).
// OUT-OF-PLACE. 1024 threads = 8 cols x 128 lanes; ~69KB LDS -> 2 blocks/CU.
// ---------------------------------------------------------------------------
template<int DIR>
__global__ __launch_bounds__(1024) void col_fft(const float2* __restrict__ in,
                                                float2* __restrict__ outp) {
    __shared__ float2 sX[8 * 513], sY[8 * 513], tw[384];
    const int t = threadIdx.x;
    const int img = blockIdx.x >> 6;
    const int u0 = (blockIdx.x & 63) << 3;
    fill_tw<DIR>(tw, t, 1024);
    const float2* ip = in + (size_t)img * NPIX + u0;
    const int sh  = (img >= 16) ? 4 : 12;   // wrap shift for sparse support
    const int lim = (img >= 16) ? 9 : 25;   // support size
    const bool sparse = (img >= 12);
    for (int f = t; f < 2048; f += 1024) {
        const int row = f >> 2, seg = f & 3;
        float4 v = make_float4(0.0f, 0.0f, 0.0f, 0.0f);
        if (!sparse || (((row + sh) & 511) < lim))
            v = *(const float4*)(ip + (size_t)row * 512 + seg * 2);
        sX[(seg * 2)     * 513 + row] = make_float2(v.x, v.y);
        sX[(seg * 2 + 1) * 513 + row] = make_float2(v.z, v.w);
    }
    __syncthreads();
    const int c = t >> 7, tt = t & 127;
    float2* R = fft512<DIR>(sX + c * 513, sY + c * 513, tw, tt);
    float4* wp = (float4*)(outp + (size_t)img * NPIX + (size_t)(u0 + c) * 512);
    for (int k = tt; k < 256; k += 128)
        wp[k] = make_float4(R[2 * k].x, R[2 * k].y,
                            R[2 * k + 1].x, R[2 * k + 1].y);
}

__device__ __forceinline__ float2 get2(const float4 a, const float4 b, int q) {
    switch (q) {
        case 0:  return make_float2(a.x, a.y);
        case 1:  return make_float2(a.z, a.w);
        case 2:  return make_float2(b.x, b.y);
        default: return make_float2(b.z, b.w);
    }
}

// ---------------------------------------------------------------------------
// FUSED Wiener combine + inverse row-FFT (pass 1 of ifft2).
// Block = (row-pair rr in [0,257), pair in [0,6)); two 128-lane halves, half
// h owns row rh (r0=rr, r1=(512-rr)&511). Each half loads ITS OWN Z rows
// coalesced and stages them in LDS; the conjugate-mirror row each half needs
// is the OTHER half's staged row -> no global re-read, no reverse-gather.
// For rr=0/256 (self-paired) h=1 duplicates and skips the store.
// ---------------------------------------------------------------------------
__global__ __launch_bounds__(256) void combine_ifft(const float2* __restrict__ T,
                                                    const float* __restrict__ w,
                                                    float2* __restrict__ P) {
    __shared__ float2 sA[2][512], sB[2][512], tw[384];
    __shared__ float2 zrow[2][2][512];  // [half][img-of-pair][v]
    const int t = threadIdx.x;
    const int h = t >> 7, tt = t & 127;
    const int rr = blockIdx.x;    // 0..256
    const int pair = blockIdx.y;  // 0..5
    const int r0 = rr, r1 = (512 - rr) & 511;
    const int rh = h ? r1 : r0;
    fill_tw<1>(tw, t, 256);
    const int i0 = 2 * pair, i1 = 2 * pair + 1;
    const int b0 = i0 / 3, b1 = i1 / 3;
    const int ch0 = i0 % 3, ch1 = i1 % 3;
    const float iw0 = 1.0f / w[b0], iw1 = 1.0f / w[b1];
    const size_t rowh = (size_t)rh * 512;
    const float4* Zv0 = (const float4*)(T + (size_t)i0 * NPIX + rowh);
    const float4* Zv1 = (const float4*)(T + (size_t)i1 * NPIX + rowh);
    const float4* K0 = (const float4*)(T + (size_t)(12 + b0) * NPIX + rowh);
    const float4* K1 = (const float4*)(T + (size_t)(12 + b1) * NPIX + rowh);
    const float4* G0 = (const float4*)(T + (size_t)(16 + ch0) * NPIX + rowh);
    const float4* G1 = (const float4*)(T + (size_t)(16 + ch1) * NPIX + rowh);

    const float4 za = Zv0[2 * tt], zb = Zv0[2 * tt + 1];
    const float4 ua = Zv1[2 * tt], ub = Zv1[2 * tt + 1];
    const float4 ka = K0[2 * tt],  kb = K0[2 * tt + 1];
    const float4 la = K1[2 * tt],  lb = K1[2 * tt + 1];
    const float4 ga = G0[2 * tt],  gb = G0[2 * tt + 1];
    const float4 ha = G1[2 * tt],  hb = G1[2 * tt + 1];
    // stage own rows for the other half's Hermitian mirror
    zrow[h][0][4 * tt + 0] = make_float2(za.x, za.y);
    zrow[h][0][4 * tt + 1] = make_float2(za.z, za.w);
    zrow[h][0][4 * tt + 2] = make_float2(zb.x, zb.y);
    zrow[h][0][4 * tt + 3] = make_float2(zb.z, zb.w);
    zrow[h][1][4 * tt + 0] = make_float2(ua.x, ua.y);
    zrow[h][1][4 * tt + 1] = make_float2(ua.z, ua.w);
    zrow[h][1][4 * tt + 2] = make_float2(ub.x, ub.y);
    zrow[h][1][4 * tt + 3] = make_float2(ub.z, ub.w);
    __syncthreads();
    const float2* Zm0 = zrow[1 - h][0];
    const float2* Zm1 = zrow[1 - h][1];
#pragma unroll
    for (int q = 0; q < 4; ++q) {
        const int c = 4 * tt + q;
        const int nc = (512 - c) & 511;
        float2 num[2];
#pragma unroll
        for (int e = 0; e < 2; ++e) {
            const float2 Zv = e ? get2(ua, ub, q) : get2(za, zb, q);
            const float2 Zn = e ? Zm1[nc] : Zm0[nc];
            const float2 K  = e ? get2(la, lb, q) : get2(ka, kb, q);
            const float dg  = (e ? get2(ha, hb, q).x : get2(ga, gb, q).x) *
                              (e ? iw1 : iw0);
            const float2 Zm = make_float2(Zn.x, -Zn.y);  // conj(Z(-u))
            const float2 Fy = make_float2(0.5f * (Zv.x + Zm.x),
                                          0.5f * (Zv.y + Zm.y));
            const float dx = Zv.x - Zm.x, dy = Zv.y - Zm.y;
            const float2 Fphi = make_float2(0.5f * dy, -0.5f * dx);
            const float kk = K.x * K.x + K.y * K.y;
            const float Om = 1.0f / (kk + dg);
            const float2 cf = make_float2(K.x * Fy.x + K.y * Fy.y,
                                          K.x * Fy.y - K.y * Fy.x);
            num[e] = make_float2(Om * (cf.x + Fphi.x), Om * (cf.y + Fphi.y));
        }
        sA[h][c] = make_float2(num[0].x - num[1].y, num[0].y + num[1].x);
    }
    __syncthreads();
    float2* R = fft512<1>(&sA[h][0], &sB[h][0], tw, tt);
    if (!(h == 1 && r1 == r0)) {
        float4* wp = (float4*)(P + (size_t)pair * NPIX + rowh);
        for (int k = tt; k < 256; k += 128)
            wp[k] = make_float4(R[2 * k].x, R[2 * k].y,
                                R[2 * k + 1].x, R[2 * k + 1].y);
    }
}

// ---------------------------------------------------------------------------
// FUSED transpose + inverse column FFT + real unpack. Column c (spatial row
// s0+c) is IFFT'd then written as two contiguous REAL output rows:
// Re -> img 2*pair, Im -> img 2*pair+1, scaled 1/N^2.
// ---------------------------------------------------------------------------
__global__ __launch_bounds__(1024) void col_ifft_unpack(const float2* __restrict__ P,
                                                        float* __restrict__ out) {
    __shared__ float2 sX[8 * 513], sY[8 * 513], tw[384];
    const int t = threadIdx.x;
    const int pair = blockIdx.x >> 6;
    const int s0 = (blockIdx.x & 63) << 3;
    fill_tw<1>(tw, t, 1024);
    const float2* ip = P + (size_t)pair * NPIX + s0;
    for (int f = t; f < 2048; f += 1024) {
        const int row = f >> 2, seg = f & 3;
        const float4 v = *(const float4*)(ip + (size_t)row * 512 + seg * 2);
        sX[(seg * 2)     * 513 + row] = make_float2(v.x, v.y);
        sX[(seg * 2 + 1) * 513 + row] = make_float2(v.z, v.w);
    }
    __syncthreads();
    const int c = t >> 7, tt = t & 127;
    float2* R = fft512<1>(sX + c * 513, sY + c * 513, tw, tt);
    const float sc = 1.0f / 262144.0f;
    float* o0 = out + (size_t)(2 * pair) * NPIX + (size_t)(s0 + c) * 512;
    float* o1 = o0 + NPIX;
    ((float4*)o0)[tt] = make_float4(R[4 * tt].x * sc, R[4 * tt + 1].x * sc,
                                    R[4 * tt + 2].x * sc, R[4 * tt + 3].x * sc);
    ((float4*)o1)[tt] = make_float4(R[4 * tt].y * sc, R[4 * tt + 1].y * sc,
                                    R[4 * tt + 2].y * sc, R[4 * tt + 3].y * sc);
}

// ---------------------------------------------------------------------------
extern "C" void kernel_launch(void* const* d_in, const int* in_sizes, int n_in,
                              void* d_out, int out_size, void* d_ws, size_t ws_size,
                              hipStream_t stream) {
    const float* y   = (const float*)d_in[0];
    const float* k   = (const float*)d_in[1];
    const float* w   = (const float*)d_in[2];
    const float* phi = (const float*)d_in[3];
    const float* wts = (const float*)d_in[4];
    float* out = (float*)d_out;

    // workspace: S = 19 imgs (pass-1) | T = 19 imgs (col-FFT out) | A3 table.
    // P (inverse pass-1 out, 6 imgs) reuses S[0..5] (S dead after col_fft).
    const size_t needed = (size_t)38 * NPIX * sizeof(float2) + 4096;  // ~76 MB
    if (ws_size < needed) return;  // clean incorrectness signal, never OOB
    float2* S = (float2*)d_ws;
    float2* T = S + (size_t)19 * NPIX;
    float*  A3 = (float*)(T + (size_t)19 * NPIX);
    float2* P = S;

    autocorr3<<<3, 256, 0, stream>>>(wts, A3);
    fwd_fft_all<<<6271, 128, 0, stream>>>(y, phi, w, k, A3, S);

    // fused transpose + column FFT: S -> T (zero rows of K/G synthesized)
    col_fft<-1><<<19 * 64, 1024, 0, stream>>>(S, T);

    // Wiener combine + inverse row-FFT: T -> P (mirror rows shared via LDS)
    combine_ifft<<<dim3(257, 6), 256, 0, stream>>>(T, w, P);

    // fused transpose + inverse column FFT + real unpack: P -> out
    col_ifft_unpack<<<6 * 64, 1024, 0, stream>>>(P, out);
}

// Round 13
// 138.142 us; speedup vs baseline: 1.5040x; 1.0054x over previous
//
#include <hip/hip_runtime.h>
#include <math.h>

#define PI_F 3.14159265358979323846f
#define NPIX 262144  // 512*512

__device__ __forceinline__ float2 cmul(float2 a, float2 b) {
    return make_float2(a.x * b.x - a.y * b.y, a.x * b.y + a.y * b.x);
}
__device__ __forceinline__ float2 cadd(float2 a, float2 b) {
    return make_float2(a.x + b.x, a.y + b.y);
}
__device__ __forceinline__ float2 csub(float2 a, float2 b) {
    return make_float2(a.x - b.x, a.y - b.y);
}

// twiddle table: tw[m] = exp(DIR * 2*pi*i * m / 512), m in [0,384).
// Exact multiples of 2pi/512, |ang| < 1.5pi -> native __sinf/__cosf accurate.
template<int DIR>
__device__ __forceinline__ void fill_tw(float2* tw, int t, int stride) {
    for (int m = t; m < 384; m += stride) {
        const float ang = (2.0f * PI_F / 512.0f) * (float)m;
        const float s = __sinf(ang), c = __cosf(ang);
        tw[m] = make_float2(c, (DIR > 0) ? s : -s);
    }
}

template<int DIR>
__device__ __forceinline__ void bfly4(float2& v0, float2& v1, float2& v2,
                                      float2& v3, const float2* tw, int m1) {
    v1 = cmul(tw[m1], v1);
    v2 = cmul(tw[2 * m1], v2);
    v3 = cmul(tw[3 * m1], v3);
    const float2 t0 = cadd(v0, v2), t1 = csub(v0, v2);
    const float2 t2 = cadd(v1, v3), t3 = csub(v1, v3);
    const float2 t3i = (DIR > 0) ? make_float2(-t3.y, t3.x)
                                 : make_float2(t3.y, -t3.x);
    v0 = cadd(t0, t2);
    v1 = cadd(t1, t3i);
    v2 = csub(t0, t2);
    v3 = csub(t1, t3i);
}

// ---------------------------------------------------------------------------
// 512-pt Stockham FFT, REGISTER-I/O variant. Inputs v_q = elem[t + 128q] in
// registers; outputs o0..o3 = elems {t, t+256, t+128, t+384} in registers
// (o0=t, o1=t+256, o2=t+128, o3=t+384). 4 internal barriers (was 6 incl.
// caller staging). Butterfly math identical to the verified fft512.
// Stage0 writes bufB; ping-pong B->A->B->A; final radix-2 reads bufA.
// Caller MUST have a barrier between filling tw/any-LDS-inputs and the call.
// bufA may alias the caller's input staging area (overwritten only after the
// stage-0 barrier, by which time all pre-call reads have completed).
// ---------------------------------------------------------------------------
template<int DIR>
__device__ __forceinline__ void fft512_reg(float2 v0, float2 v1, float2 v2,
                                           float2 v3, float2* bufA,
                                           float2* bufB, const float2* tw,
                                           int t, float2& o0, float2& o1,
                                           float2& o2, float2& o3) {
    // stage 0: Ns=1, jm=0, od=4t (twiddle = tw[0] = 1, kept for parity)
    bfly4<DIR>(v0, v1, v2, v3, tw, 0);
    {
        const int od = t << 2;
        bufB[od] = v0; bufB[od + 1] = v1; bufB[od + 2] = v2; bufB[od + 3] = v3;
    }
    __syncthreads();
    float2* X = bufB;
    float2* Y = bufA;
    int Ns = 4;
#pragma unroll
    for (int s = 0; s < 3; ++s) {  // Ns = 4, 16, 64
        const int jm = t & (Ns - 1);
        const int jd = t - jm;
        float2 a0 = X[t], a1 = X[t + 128], a2 = X[t + 256], a3 = X[t + 384];
        const int m1 = jm * (128 / Ns);
        bfly4<DIR>(a0, a1, a2, a3, tw, m1);
        const int od = (jd << 2) + jm;  // expand(j, Ns, 4)
        Y[od] = a0; Y[od + Ns] = a1; Y[od + 2 * Ns] = a2; Y[od + 3 * Ns] = a3;
        __syncthreads();
        float2* tmp = X; X = Y; Y = tmp;
        Ns <<= 2;
    }
    // X = bufA here. Final radix-2, Ns=256: j = t and t+128.
    const float2 a0 = X[t],       b0 = X[t + 256];
    const float2 a1 = X[t + 128], b1 = X[t + 384];
    const float2 u0 = cmul(tw[t], b0);
    const float2 u1 = cmul(tw[t + 128], b1);
    o0 = cadd(a0, u0);  // elem t
    o1 = csub(a0, u0);  // elem t+256
    o2 = cadd(a1, u1);  // elem t+128
    o3 = csub(a1, u1);  // elem t+384
}

// ---------------------------------------------------------------------------
// Per-channel summed autocorrelation of weights -> A3[3][81] (9x9 support).
// ---------------------------------------------------------------------------
__global__ __launch_bounds__(256) void autocorr3(const float* __restrict__ wts,
                                                 float* __restrict__ A3) {
    const int ch = blockIdx.x, tid = threadIdx.x;
    __shared__ float gp[24][13][13];
    __shared__ float part[243];
    float* gpf = &gp[0][0][0];
    for (int i = tid; i < 24 * 169; i += 256) gpf[i] = 0.0f;
    __syncthreads();
    for (int i = tid; i < 600; i += 256) {
        const int f = i / 25, rem = i % 25;
        const int x = rem / 5, yy = rem % 5;
        gp[f][x + 4][yy + 4] = wts[(size_t)(f * 3 + ch) * 25 + rem];
    }
    __syncthreads();
    if (tid < 243) {
        const int dpos = tid / 3, seg = tid % 3;
        const int di = dpos / 9 - 4, dj = dpos % 9 - 4;
        float acc = 0.0f;
        for (int f = seg * 8; f < seg * 8 + 8; ++f) {
#pragma unroll
            for (int x = 0; x < 5; ++x)
#pragma unroll
                for (int yy = 0; yy < 5; ++yy)
                    acc += gp[f][x + 4][yy + 4] *
                           gp[f][x + di + 4][yy + dj + 4];
        }
        part[tid] = acc;
    }
    __syncthreads();
    if (tid < 81)
        A3[ch * 81 + tid] = part[tid * 3] + part[tid * 3 + 1] + part[tid * 3 + 2];
}

// ---------------------------------------------------------------------------
// Forward pass 1, merged. Blocks 0..6143: row FFT of (y + i*phi/w[b]) —
// inputs loaded STRAIGHT to stage-0 registers (strided 4B coalesced loads,
// no input LDS staging). Blocks 6144..6270: K/G sparse rows synthesized
// directly in registers (taps only land in v0/v3). Dense spectral rows out.
// ---------------------------------------------------------------------------
__global__ __launch_bounds__(128) void fwd_fft_all(const float* __restrict__ y,
                                                   const float* __restrict__ phi,
                                                   const float* __restrict__ w,
                                                   const float* __restrict__ kin,
                                                   const float* __restrict__ A3,
                                                   float2* __restrict__ S) {
    __shared__ float2 sA[512], sB[512], tw[384];
    const int t = threadIdx.x;
    fill_tw<-1>(tw, t, 128);
    float2 v0, v1, v2, v3;
    size_t off;
    if (blockIdx.x < 6144) {
        const int img = blockIdx.x >> 9, row = blockIdx.x & 511;
        off = (size_t)img * NPIX + (size_t)row * 512;
        const float iwv = 1.0f / w[img / 3];
        v0 = make_float2(y[off + t],       phi[off + t] * iwv);
        v1 = make_float2(y[off + t + 128], phi[off + t + 128] * iwv);
        v2 = make_float2(y[off + t + 256], phi[off + t + 256] * iwv);
        v3 = make_float2(y[off + t + 384], phi[off + t + 384] * iwv);
    } else {
        const int bid = (int)blockIdx.x - 6144;  // 0..126
        int img, row;
        v1 = v2 = make_float2(0.0f, 0.0f);
        if (bid < 100) {  // K: taps at cols (j-12)&511, j<25
            const int b = bid / 25, i = bid % 25;
            img = 12 + b;
            row = (i - 12) & 511;
            const float* kr = kin + b * 625 + i * 25;
            v0 = make_float2((t <= 12)  ? kr[t + 12]  : 0.0f, 0.0f);
            v3 = make_float2((t >= 116) ? kr[t - 116] : 0.0f, 0.0f);
        } else {          // G: taps at cols (j-4)&511, j<9
            const int g = bid - 100;
            const int ch = g / 9, di = g % 9;
            img = 16 + ch;
            row = (di - 4) & 511;
            const float* ar = A3 + ch * 81 + di * 9;
            v0 = make_float2((t < 5)    ? ar[t + 4]   : 0.0f, 0.0f);
            v3 = make_float2((t >= 124) ? ar[t - 124] : 0.0f, 0.0f);
        }
        off = (size_t)img * NPIX + (size_t)row * 512;
    }
    __syncthreads();  // tw ready
    float2 o0, o1, o2, o3;
    fft512_reg<-1>(v0, v1, v2, v3, sA, sB, tw, t, o0, o1, o2, o3);
    float2* rp = S + off;
    rp[t] = o0; rp[t + 128] = o2; rp[t + 256] = o1; rp[t + 384] = o3;
}

// ---------------------------------------------------------------------------
// FUSED transpose + column FFT. Block = (img, 8-column tile): reads the
// strip via 64B row segments into the LDS tile (the transpose), FFTs the 8
// columns (register-I/O core; tile doubles as bufA), writes each column's
// result as a CONTIGUOUS row from registers. K/G zero rows synthesized.
// OUT-OF-PLACE. 1024 threads = 8 cols x 128 lanes; ~69KB LDS -> 2 blocks/CU.
// ---------------------------------------------------------------------------
template<int DIR>
__global__ __launch_bounds__(1024) void col_fft(const float2* __restrict__ in,
                                                float2* __restrict__ outp) {
    __shared__ float2 sX[8 * 513], sY[8 * 513], tw[384];
    const int t = threadIdx.x;
    const int img = blockIdx.x >> 6;
    const int u0 = (blockIdx.x & 63) << 3;
    fill_tw<DIR>(tw, t, 1024);
    const float2* ip = in + (size_t)img * NPIX + u0;
    const int sh  = (img >= 16) ? 4 : 12;   // wrap shift for sparse support
    const int lim = (img >= 16) ? 9 : 25;   // support size
    const bool sparse = (img >= 12);
    for (int f = t; f < 2048; f += 1024) {
        const int row = f >> 2, seg = f & 3;
        float4 v = make_float4(0.0f, 0.0f, 0.0f, 0.0f);
        if (!sparse || (((row + sh) & 511) < lim))
            v = *(const float4*)(ip + (size_t)row * 512 + seg * 2);
        sX[(seg * 2)     * 513 + row] = make_float2(v.x, v.y);
        sX[(seg * 2 + 1) * 513 + row] = make_float2(v.z, v.w);
    }
    __syncthreads();
    const int c = t >> 7, tt = t & 127;
    float2* X = sX + c * 513;
    const float2 v0 = X[tt], v1 = X[tt + 128], v2 = X[tt + 256], v3 = X[tt + 384];
    float2 o0, o1, o2, o3;
    fft512_reg<DIR>(v0, v1, v2, v3, X, sY + c * 513, tw, tt, o0, o1, o2, o3);
    float2* wp = outp + (size_t)img * NPIX + (size_t)(u0 + c) * 512;
    wp[tt] = o0; wp[tt + 128] = o2; wp[tt + 256] = o1; wp[tt + 384] = o3;
}

__device__ __forceinline__ float2 get2(const float4 a, const float4 b, int q) {
    switch (q) {
        case 0:  return make_float2(a.x, a.y);
        case 1:  return make_float2(a.z, a.w);
        case 2:  return make_float2(b.x, b.y);
        default: return make_float2(b.z, b.w);
    }
}

// ---------------------------------------------------------------------------
// FUSED Wiener combine + inverse row-FFT (pass 1 of ifft2).
// Block = (row-pair rr in [0,257), pair in [0,6)); two 128-lane halves, half
// h owns row rh (r0=rr, r1=(512-rr)&511). Mirror rows shared via LDS (no
// global re-read). Packs pair as num0 + i*num1, inverse FFT with register
// output. For rr=0/256 h=1 duplicates and skips the store.
// ---------------------------------------------------------------------------
__global__ __launch_bounds__(256) void combine_ifft(const float2* __restrict__ T,
                                                    const float* __restrict__ w,
                                                    float2* __restrict__ P) {
    __shared__ float2 sA[2][512], sB[2][512], tw[384];
    __shared__ float2 zrow[2][2][512];  // [half][img-of-pair][v]
    const int t = threadIdx.x;
    const int h = t >> 7, tt = t & 127;
    const int rr = blockIdx.x;    // 0..256
    const int pair = blockIdx.y;  // 0..5
    const int r0 = rr, r1 = (512 - rr) & 511;
    const int rh = h ? r1 : r0;
    fill_tw<1>(tw, t, 256);
    const int i0 = 2 * pair, i1 = 2 * pair + 1;
    const int b0 = i0 / 3, b1 = i1 / 3;
    const int ch0 = i0 % 3, ch1 = i1 % 3;
    const float iw0 = 1.0f / w[b0], iw1 = 1.0f / w[b1];
    const size_t rowh = (size_t)rh * 512;
    const float4* Zv0 = (const float4*)(T + (size_t)i0 * NPIX + rowh);
    const float4* Zv1 = (const float4*)(T + (size_t)i1 * NPIX + rowh);
    const float4* K0 = (const float4*)(T + (size_t)(12 + b0) * NPIX + rowh);
    const float4* K1 = (const float4*)(T + (size_t)(12 + b1) * NPIX + rowh);
    const float4* G0 = (const float4*)(T + (size_t)(16 + ch0) * NPIX + rowh);
    const float4* G1 = (const float4*)(T + (size_t)(16 + ch1) * NPIX + rowh);

    const float4 za = Zv0[2 * tt], zb = Zv0[2 * tt + 1];
    const float4 ua = Zv1[2 * tt], ub = Zv1[2 * tt + 1];
    const float4 ka = K0[2 * tt],  kb = K0[2 * tt + 1];
    const float4 la = K1[2 * tt],  lb = K1[2 * tt + 1];
    const float4 ga = G0[2 * tt],  gb = G0[2 * tt + 1];
    const float4 ha = G1[2 * tt],  hb = G1[2 * tt + 1];
    // stage own rows for the other half's Hermitian mirror
    zrow[h][0][4 * tt + 0] = make_float2(za.x, za.y);
    zrow[h][0][4 * tt + 1] = make_float2(za.z, za.w);
    zrow[h][0][4 * tt + 2] = make_float2(zb.x, zb.y);
    zrow[h][0][4 * tt + 3] = make_float2(zb.z, zb.w);
    zrow[h][1][4 * tt + 0] = make_float2(ua.x, ua.y);
    zrow[h][1][4 * tt + 1] = make_float2(ua.z, ua.w);
    zrow[h][1][4 * tt + 2] = make_float2(ub.x, ub.y);
    zrow[h][1][4 * tt + 3] = make_float2(ub.z, ub.w);
    __syncthreads();
    const float2* Zm0 = zrow[1 - h][0];
    const float2* Zm1 = zrow[1 - h][1];
#pragma unroll
    for (int q = 0; q < 4; ++q) {
        const int c = 4 * tt + q;
        const int nc = (512 - c) & 511;
        float2 num[2];
#pragma unroll
        for (int e = 0; e < 2; ++e) {
            const float2 Zv = e ? get2(ua, ub, q) : get2(za, zb, q);
            const float2 Zn = e ? Zm1[nc] : Zm0[nc];
            const float2 K  = e ? get2(la, lb, q) : get2(ka, kb, q);
            const float dg  = (e ? get2(ha, hb, q).x : get2(ga, gb, q).x) *
                              (e ? iw1 : iw0);
            const float2 Zm = make_float2(Zn.x, -Zn.y);  // conj(Z(-u))
            const float2 Fy = make_float2(0.5f * (Zv.x + Zm.x),
                                          0.5f * (Zv.y + Zm.y));
            const float dx = Zv.x - Zm.x, dy = Zv.y - Zm.y;
            const float2 Fphi = make_float2(0.5f * dy, -0.5f * dx);
            const float kk = K.x * K.x + K.y * K.y;
            const float Om = 1.0f / (kk + dg);
            const float2 cf = make_float2(K.x * Fy.x + K.y * Fy.y,
                                          K.x * Fy.y - K.y * Fy.x);
            num[e] = make_float2(Om * (cf.x + Fphi.x), Om * (cf.y + Fphi.y));
        }
        sA[h][c] = make_float2(num[0].x - num[1].y, num[0].y + num[1].x);
    }
    __syncthreads();
    const float2 v0 = sA[h][tt],       v1 = sA[h][tt + 128];
    const float2 v2 = sA[h][tt + 256], v3 = sA[h][tt + 384];
    float2 o0, o1, o2, o3;
    fft512_reg<1>(v0, v1, v2, v3, &sA[h][0], &sB[h][0], tw, tt, o0, o1, o2, o3);
    if (!(h == 1 && r1 == r0)) {
        float2* wp = P + (size_t)pair * NPIX + rowh;
        wp[tt] = o0; wp[tt + 128] = o2; wp[tt + 256] = o1; wp[tt + 384] = o3;
    }
}

// ---------------------------------------------------------------------------
// FUSED transpose + inverse column FFT + real unpack. Column c (spatial row
// s0+c) IFFT'd, results written from registers as two REAL rows:
// Re -> img 2*pair, Im -> img 2*pair+1, scaled 1/N^2 (4B coalesced stores).
// ---------------------------------------------------------------------------
__global__ __launch_bounds__(1024) void col_ifft_unpack(const float2* __restrict__ P,
                                                        float* __restrict__ out) {
    __shared__ float2 sX[8 * 513], sY[8 * 513], tw[384];
    const int t = threadIdx.x;
    const int pair = blockIdx.x >> 6;
    const int s0 = (blockIdx.x & 63) << 3;
    fill_tw<1>(tw, t, 1024);
    const float2* ip = P + (size_t)pair * NPIX + s0;
    for (int f = t; f < 2048; f += 1024) {
        const int row = f >> 2, seg = f & 3;
        const float4 v = *(const float4*)(ip + (size_t)row * 512 + seg * 2);
        sX[(seg * 2)     * 513 + row] = make_float2(v.x, v.y);
        sX[(seg * 2 + 1) * 513 + row] = make_float2(v.z, v.w);
    }
    __syncthreads();
    const int c = t >> 7, tt = t & 127;
    float2* X = sX + c * 513;
    const float2 v0 = X[tt], v1 = X[tt + 128], v2 = X[tt + 256], v3 = X[tt + 384];
    float2 o0, o1, o2, o3;
    fft512_reg<1>(v0, v1, v2, v3, X, sY + c * 513, tw, tt, o0, o1, o2, o3);
    const float sc = 1.0f / 262144.0f;
    float* oa = out + (size_t)(2 * pair) * NPIX + (size_t)(s0 + c) * 512;
    float* ob = oa + NPIX;
    oa[tt] = o0.x * sc; oa[tt + 128] = o2.x * sc;
    oa[tt + 256] = o1.x * sc; oa[tt + 384] = o3.x * sc;
    ob[tt] = o0.y * sc; ob[tt + 128] = o2.y * sc;
    ob[tt + 256] = o1.y * sc; ob[tt + 384] = o3.y * sc;
}

// ---------------------------------------------------------------------------
extern "C" void kernel_launch(void* const* d_in, const int* in_sizes, int n_in,
                              void* d_out, int out_size, void* d_ws, size_t ws_size,
                              hipStream_t stream) {
    const float* y   = (const float*)d_in[0];
    const float* k   = (const float*)d_in[1];
    const float* w   = (const float*)d_in[2];
    const float* phi = (const float*)d_in[3];
    const float* wts = (const float*)d_in[4];
    float* out = (float*)d_out;

    // workspace: S = 19 imgs (pass-1) | T = 19 imgs (col-FFT out) | A3 table.
    // P (inverse pass-1 out, 6 imgs) reuses S[0..5] (S dead after col_fft).
    const size_t needed = (size_t)38 * NPIX * sizeof(float2) + 4096;  // ~76 MB
    if (ws_size < needed) return;  // clean incorrectness signal, never OOB
    float2* S = (float2*)d_ws;
    float2* T = S + (size_t)19 * NPIX;
    float*  A3 = (float*)(T + (size_t)19 * NPIX);
    float2* P = S;

    autocorr3<<<3, 256, 0, stream>>>(wts, A3);
    fwd_fft_all<<<6271, 128, 0, stream>>>(y, phi, w, k, A3, S);

    // fused transpose + column FFT: S -> T (zero rows of K/G synthesized)
    col_fft<-1><<<19 * 64, 1024, 0, stream>>>(S, T);

    // Wiener combine + inverse row-FFT: T -> P (mirror rows shared via LDS)
    combine_ifft<<<dim3(257, 6), 256, 0, stream>>>(T, w, P);

    // fused transpose + inverse column FFT + real unpack: P -> out
    col_ifft_unpack<<<6 * 64, 1024, 0, stream>>>(P, out);
}

// Round 14
// 134.148 us; speedup vs baseline: 1.5488x; 1.0298x over previous
//
#include <hip/hip_runtime.h>
#include <math.h>

#define PI_F 3.14159265358979323846f
#define NPIX 262144  // 512*512

__device__ __forceinline__ float2 cmul(float2 a, float2 b) {
    return make_float2(a.x * b.x - a.y * b.y, a.x * b.y + a.y * b.x);
}
__device__ __forceinline__ float2 cadd(float2 a, float2 b) {
    return make_float2(a.x + b.x, a.y + b.y);
}
__device__ __forceinline__ float2 csub(float2 a, float2 b) {
    return make_float2(a.x - b.x, a.y - b.y);
}

// twiddle table: tw[m] = exp(DIR * 2*pi*i * m / 512), m in [0,384).
// Exact multiples of 2pi/512, |ang| < 1.5pi -> native __sinf/__cosf accurate.
template<int DIR>
__device__ __forceinline__ void fill_tw(float2* tw, int t, int stride) {
    for (int m = t; m < 384; m += stride) {
        const float ang = (2.0f * PI_F / 512.0f) * (float)m;
        const float s = __sinf(ang), c = __cosf(ang);
        tw[m] = make_float2(c, (DIR > 0) ? s : -s);
    }
}

template<int DIR>
__device__ __forceinline__ void bfly4(float2& v0, float2& v1, float2& v2,
                                      float2& v3, const float2* tw, int m1) {
    v1 = cmul(tw[m1], v1);
    v2 = cmul(tw[2 * m1], v2);
    v3 = cmul(tw[3 * m1], v3);
    const float2 t0 = cadd(v0, v2), t1 = csub(v0, v2);
    const float2 t2 = cadd(v1, v3), t3 = csub(v1, v3);
    const float2 t3i = (DIR > 0) ? make_float2(-t3.y, t3.x)
                                 : make_float2(t3.y, -t3.x);
    v0 = cadd(t0, t2);
    v1 = cadd(t1, t3i);
    v2 = csub(t0, t2);
    v3 = csub(t1, t3i);
}

// ---------------------------------------------------------------------------
// 512-pt Stockham FFT, REGISTER-I/O variant. Inputs v_q = elem[t + 128q] in
// registers; outputs o0..o3 = elems {t, t+256, t+128, t+384} in registers.
// 4 internal barriers. Stage0 writes bufB; ping-pong B->A->B->A; final
// radix-2 reads bufA. Caller must barrier between LDS-input fill and call.
// bufA may alias caller staging (overwritten only after stage-0 barrier).
// ---------------------------------------------------------------------------
template<int DIR>
__device__ __forceinline__ void fft512_reg(float2 v0, float2 v1, float2 v2,
                                           float2 v3, float2* bufA,
                                           float2* bufB, const float2* tw,
                                           int t, float2& o0, float2& o1,
                                           float2& o2, float2& o3) {
    bfly4<DIR>(v0, v1, v2, v3, tw, 0);  // stage 0: Ns=1, jm=0
    {
        const int od = t << 2;
        bufB[od] = v0; bufB[od + 1] = v1; bufB[od + 2] = v2; bufB[od + 3] = v3;
    }
    __syncthreads();
    float2* X = bufB;
    float2* Y = bufA;
    int Ns = 4;
#pragma unroll
    for (int s = 0; s < 3; ++s) {  // Ns = 4, 16, 64
        const int jm = t & (Ns - 1);
        const int jd = t - jm;
        float2 a0 = X[t], a1 = X[t + 128], a2 = X[t + 256], a3 = X[t + 384];
        const int m1 = jm * (128 / Ns);
        bfly4<DIR>(a0, a1, a2, a3, tw, m1);
        const int od = (jd << 2) + jm;  // expand(j, Ns, 4)
        Y[od] = a0; Y[od + Ns] = a1; Y[od + 2 * Ns] = a2; Y[od + 3 * Ns] = a3;
        __syncthreads();
        float2* tmp = X; X = Y; Y = tmp;
        Ns <<= 2;
    }
    // X = bufA. Final radix-2, Ns=256: j = t and t+128.
    const float2 a0 = X[t],       b0 = X[t + 256];
    const float2 a1 = X[t + 128], b1 = X[t + 384];
    const float2 u0 = cmul(tw[t], b0);
    const float2 u1 = cmul(tw[t + 128], b1);
    o0 = cadd(a0, u0);  // elem t
    o1 = csub(a0, u0);  // elem t+256
    o2 = cadd(a1, u1);  // elem t+128
    o3 = csub(a1, u1);  // elem t+384
}

// ---------------------------------------------------------------------------
// Forward pass 1, merged. Blocks 0..6143: row FFT of (y + i*phi/w[b]) —
// inputs straight to stage-0 registers. Blocks 6144..6243: K sparse rows
// from kin (register synthesis). Blocks 6244..6270: G rows — the block
// computes ITS OWN autocorr row in-block (taps staged in the still-unused
// sB buffer -> zero LDS growth; 108 threads x 50 predicated LDS-FMAs,
// branch-free), then FFTs it. Replaces the separate autocorr3 launch.
// ---------------------------------------------------------------------------
__global__ __launch_bounds__(128) void fwd_fft_all(const float* __restrict__ y,
                                                   const float* __restrict__ phi,
                                                   const float* __restrict__ w,
                                                   const float* __restrict__ kin,
                                                   const float* __restrict__ wts,
                                                   float2* __restrict__ S) {
    __shared__ float2 sA[512], sB[512], tw[384];
    const int t = threadIdx.x;
    fill_tw<-1>(tw, t, 128);
    float2 v0, v1, v2, v3;
    size_t off;
    if (blockIdx.x < 6144) {
        const int img = blockIdx.x >> 9, row = blockIdx.x & 511;
        off = (size_t)img * NPIX + (size_t)row * 512;
        const float iwv = 1.0f / w[img / 3];
        v0 = make_float2(y[off + t],       phi[off + t] * iwv);
        v1 = make_float2(y[off + t + 128], phi[off + t + 128] * iwv);
        v2 = make_float2(y[off + t + 256], phi[off + t + 256] * iwv);
        v3 = make_float2(y[off + t + 384], phi[off + t + 384] * iwv);
    } else {
        const int bid = (int)blockIdx.x - 6144;  // 0..126
        int img, row;
        v1 = v2 = make_float2(0.0f, 0.0f);
        if (bid < 100) {  // K: taps at cols (j-12)&511, j<25
            const int b = bid / 25, i = bid % 25;
            img = 12 + b;
            row = (i - 12) & 511;
            const float* kr = kin + b * 625 + i * 25;
            v0 = make_float2((t <= 12)  ? kr[t + 12]  : 0.0f, 0.0f);
            v3 = make_float2((t >= 116) ? kr[t - 116] : 0.0f, 0.0f);
        } else {          // G: autocorr row di computed in-block
            const int g = bid - 100;
            const int ch = g / 9, di = g % 9;   // di = row idx in [0,9)
            img = 16 + ch;
            row = (di - 4) & 511;
            float* sBf = (float*)sB;  // tap staging (600 floats < 1024)
            float* sAf = (float*)sA;  // partials [0..107], results [1000..1008]
            // stage channel-ch taps: sBf[f*25 + x*5 + y] = wts[f][ch][x][y]
            for (int i = t; i < 600; i += 128) {
                const int f = i / 25, rem = i % 25;
                sBf[i] = wts[(size_t)(f * 3 + ch) * 25 + rem];
            }
            __syncthreads();
            const int di4 = di - 4;
            if (t < 108) {  // dj = t/12, filters {2seg, 2seg+1}
                const int dj = t / 12, seg = t % 12;
                const int dj4 = dj - 4;
                float acc = 0.0f;
#pragma unroll
                for (int fo = 0; fo < 2; ++fo) {
                    const float* gf = sBf + (2 * seg + fo) * 25;
#pragma unroll
                    for (int x = 0; x < 5; ++x) {
                        const int x2 = x + di4;
                        const bool xok = (x2 >= 0) && (x2 < 5);
#pragma unroll
                        for (int yy = 0; yy < 5; ++yy) {
                            const int y2 = yy + dj4;
                            const bool ok = xok && (y2 >= 0) && (y2 < 5);
                            acc += ok ? gf[x * 5 + yy] * gf[x2 * 5 + y2] : 0.0f;
                        }
                    }
                }
                sAf[t] = acc;
            }
            __syncthreads();
            if (t < 9) {
                float s = 0.0f;
#pragma unroll
                for (int q = 0; q < 12; ++q) s += sAf[t * 12 + q];
                sAf[1000 + t] = s;
            }
            __syncthreads();
            v0 = make_float2((t < 5)    ? sAf[1000 + t + 4]   : 0.0f, 0.0f);
            v3 = make_float2((t >= 124) ? sAf[1000 + t - 124] : 0.0f, 0.0f);
        }
        off = (size_t)img * NPIX + (size_t)row * 512;
    }
    __syncthreads();  // tw ready (and G-path LDS consumed into registers)
    float2 o0, o1, o2, o3;
    fft512_reg<-1>(v0, v1, v2, v3, sA, sB, tw, t, o0, o1, o2, o3);
    float2* rp = S + off;
    rp[t] = o0; rp[t + 128] = o2; rp[t + 256] = o1; rp[t + 384] = o3;
}

// ---------------------------------------------------------------------------
// FUSED transpose + column FFT. Block = (img, 8-column tile): reads the
// strip via 64B row segments into the LDS tile (the transpose), FFTs the 8
// columns (register-I/O core; tile doubles as bufA), writes each column's
// result as a CONTIGUOUS row from registers. K/G zero rows synthesized.
// OUT-OF-PLACE. 1024 threads = 8 cols x 128 lanes; ~69KB LDS -> 2 blocks/CU.
// ---------------------------------------------------------------------------
template<int DIR>
__global__ __launch_bounds__(1024) void col_fft(const float2* __restrict__ in,
                                                float2* __restrict__ outp) {
    __shared__ float2 sX[8 * 513], sY[8 * 513], tw[384];
    const int t = threadIdx.x;
    const int img = blockIdx.x >> 6;
    const int u0 = (blockIdx.x & 63) << 3;
    fill_tw<DIR>(tw, t, 1024);
    const float2* ip = in + (size_t)img * NPIX + u0;
    const int sh  = (img >= 16) ? 4 : 12;   // wrap shift for sparse support
    const int lim = (img >= 16) ? 9 : 25;   // support size
    const bool sparse = (img >= 12);
    for (int f = t; f < 2048; f += 1024) {
        const int row = f >> 2, seg = f & 3;
        float4 v = make_float4(0.0f, 0.0f, 0.0f, 0.0f);
        if (!sparse || (((row + sh) & 511) < lim))
            v = *(const float4*)(ip + (size_t)row * 512 + seg * 2);
        sX[(seg * 2)     * 513 + row] = make_float2(v.x, v.y);
        sX[(seg * 2 + 1) * 513 + row] = make_float2(v.z, v.w);
    }
    __syncthreads();
    const int c = t >> 7, tt = t & 127;
    float2* X = sX + c * 513;
    const float2 v0 = X[tt], v1 = X[tt + 128], v2 = X[tt + 256], v3 = X[tt + 384];
    float2 o0, o1, o2, o3;
    fft512_reg<DIR>(v0, v1, v2, v3, X, sY + c * 513, tw, tt, o0, o1, o2, o3);
    float2* wp = outp + (size_t)img * NPIX + (size_t)(u0 + c) * 512;
    wp[tt] = o0; wp[tt + 128] = o2; wp[tt + 256] = o1; wp[tt + 384] = o3;
}

__device__ __forceinline__ float2 get2(const float4 a, const float4 b, int q) {
    switch (q) {
        case 0:  return make_float2(a.x, a.y);
        case 1:  return make_float2(a.z, a.w);
        case 2:  return make_float2(b.x, b.y);
        default: return make_float2(b.z, b.w);
    }
}

// ---------------------------------------------------------------------------
// FUSED Wiener combine + inverse row-FFT (pass 1 of ifft2).
// Block = (row-pair rr in [0,257), pair in [0,6)); two 128-lane halves, half
// h owns row rh (r0=rr, r1=(512-rr)&511). Mirror rows shared via LDS (no
// global re-read). Packs pair as num0 + i*num1, inverse FFT with register
// output. For rr=0/256 h=1 duplicates and skips the store.
// ---------------------------------------------------------------------------
__global__ __launch_bounds__(256) void combine_ifft(const float2* __restrict__ T,
                                                    const float* __restrict__ w,
                                                    float2* __restrict__ P) {
    __shared__ float2 sA[2][512], sB[2][512], tw[384];
    __shared__ float2 zrow[2][2][512];  // [half][img-of-pair][v]
    const int t = threadIdx.x;
    const int h = t >> 7, tt = t & 127;
    const int rr = blockIdx.x;    // 0..256
    const int pair = blockIdx.y;  // 0..5
    const int r0 = rr, r1 = (512 - rr) & 511;
    const int rh = h ? r1 : r0;
    fill_tw<1>(tw, t, 256);
    const int i0 = 2 * pair, i1 = 2 * pair + 1;
    const int b0 = i0 / 3, b1 = i1 / 3;
    const int ch0 = i0 % 3, ch1 = i1 % 3;
    const float iw0 = 1.0f / w[b0], iw1 = 1.0f / w[b1];
    const size_t rowh = (size_t)rh * 512;
    const float4* Zv0 = (const float4*)(T + (size_t)i0 * NPIX + rowh);
    const float4* Zv1 = (const float4*)(T + (size_t)i1 * NPIX + rowh);
    const float4* K0 = (const float4*)(T + (size_t)(12 + b0) * NPIX + rowh);
    const float4* K1 = (const float4*)(T + (size_t)(12 + b1) * NPIX + rowh);
    const float4* G0 = (const float4*)(T + (size_t)(16 + ch0) * NPIX + rowh);
    const float4* G1 = (const float4*)(T + (size_t)(16 + ch1) * NPIX + rowh);

    const float4 za = Zv0[2 * tt], zb = Zv0[2 * tt + 1];
    const float4 ua = Zv1[2 * tt], ub = Zv1[2 * tt + 1];
    const float4 ka = K0[2 * tt],  kb = K0[2 * tt + 1];
    const float4 la = K1[2 * tt],  lb = K1[2 * tt + 1];
    const float4 ga = G0[2 * tt],  gb = G0[2 * tt + 1];
    const float4 ha = G1[2 * tt],  hb = G1[2 * tt + 1];
    // stage own rows for the other half's Hermitian mirror
    zrow[h][0][4 * tt + 0] = make_float2(za.x, za.y);
    zrow[h][0][4 * tt + 1] = make_float2(za.z, za.w);
    zrow[h][0][4 * tt + 2] = make_float2(zb.x, zb.y);
    zrow[h][0][4 * tt + 3] = make_float2(zb.z, zb.w);
    zrow[h][1][4 * tt + 0] = make_float2(ua.x, ua.y);
    zrow[h][1][4 * tt + 1] = make_float2(ua.z, ua.w);
    zrow[h][1][4 * tt + 2] = make_float2(ub.x, ub.y);
    zrow[h][1][4 * tt + 3] = make_float2(ub.z, ub.w);
    __syncthreads();
    const float2* Zm0 = zrow[1 - h][0];
    const float2* Zm1 = zrow[1 - h][1];
#pragma unroll
    for (int q = 0; q < 4; ++q) {
        const int c = 4 * tt + q;
        const int nc = (512 - c) & 511;
        float2 num[2];
#pragma unroll
        for (int e = 0; e < 2; ++e) {
            const float2 Zv = e ? get2(ua, ub, q) : get2(za, zb, q);
            const float2 Zn = e ? Zm1[nc] : Zm0[nc];
            const float2 K  = e ? get2(la, lb, q) : get2(ka, kb, q);
            const float dg  = (e ? get2(ha, hb, q).x : get2(ga, gb, q).x) *
                              (e ? iw1 : iw0);
            const float2 Zm = make_float2(Zn.x, -Zn.y);  // conj(Z(-u))
            const float2 Fy = make_float2(0.5f * (Zv.x + Zm.x),
                                          0.5f * (Zv.y + Zm.y));
            const float dx = Zv.x - Zm.x, dy = Zv.y - Zm.y;
            const float2 Fphi = make_float2(0.5f * dy, -0.5f * dx);
            const float kk = K.x * K.x + K.y * K.y;
            const float Om = 1.0f / (kk + dg);
            const float2 cf = make_float2(K.x * Fy.x + K.y * Fy.y,
                                          K.x * Fy.y - K.y * Fy.x);
            num[e] = make_float2(Om * (cf.x + Fphi.x), Om * (cf.y + Fphi.y));
        }
        sA[h][c] = make_float2(num[0].x - num[1].y, num[0].y + num[1].x);
    }
    __syncthreads();
    const float2 v0 = sA[h][tt],       v1 = sA[h][tt + 128];
    const float2 v2 = sA[h][tt + 256], v3 = sA[h][tt + 384];
    float2 o0, o1, o2, o3;
    fft512_reg<1>(v0, v1, v2, v3, &sA[h][0], &sB[h][0], tw, tt, o0, o1, o2, o3);
    if (!(h == 1 && r1 == r0)) {
        float2* wp = P + (size_t)pair * NPIX + rowh;
        wp[tt] = o0; wp[tt + 128] = o2; wp[tt + 256] = o1; wp[tt + 384] = o3;
    }
}

// ---------------------------------------------------------------------------
// FUSED transpose + inverse column FFT + real unpack. Column c (spatial row
// s0+c) IFFT'd, results written from registers as two REAL rows:
// Re -> img 2*pair, Im -> img 2*pair+1, scaled 1/N^2 (4B coalesced stores).
// ---------------------------------------------------------------------------
__global__ __launch_bounds__(1024) void col_ifft_unpack(const float2* __restrict__ P,
                                                        float* __restrict__ out) {
    __shared__ float2 sX[8 * 513], sY[8 * 513], tw[384];
    const int t = threadIdx.x;
    const int pair = blockIdx.x >> 6;
    const int s0 = (blockIdx.x & 63) << 3;
    fill_tw<1>(tw, t, 1024);
    const float2* ip = P + (size_t)pair * NPIX + s0;
    for (int f = t; f < 2048; f += 1024) {
        const int row = f >> 2, seg = f & 3;
        const float4 v = *(const float4*)(ip + (size_t)row * 512 + seg * 2);
        sX[(seg * 2)     * 513 + row] = make_float2(v.x, v.y);
        sX[(seg * 2 + 1) * 513 + row] = make_float2(v.z, v.w);
    }
    __syncthreads();
    const int c = t >> 7, tt = t & 127;
    float2* X = sX + c * 513;
    const float2 v0 = X[tt], v1 = X[tt + 128], v2 = X[tt + 256], v3 = X[tt + 384];
    float2 o0, o1, o2, o3;
    fft512_reg<1>(v0, v1, v2, v3, X, sY + c * 513, tw, tt, o0, o1, o2, o3);
    const float sc = 1.0f / 262144.0f;
    float* oa = out + (size_t)(2 * pair) * NPIX + (size_t)(s0 + c) * 512;
    float* ob = oa + NPIX;
    oa[tt] = o0.x * sc; oa[tt + 128] = o2.x * sc;
    oa[tt + 256] = o1.x * sc; oa[tt + 384] = o3.x * sc;
    ob[tt] = o0.y * sc; ob[tt + 128] = o2.y * sc;
    ob[tt + 256] = o1.y * sc; ob[tt + 384] = o3.y * sc;
}

// ---------------------------------------------------------------------------
extern "C" void kernel_launch(void* const* d_in, const int* in_sizes, int n_in,
                              void* d_out, int out_size, void* d_ws, size_t ws_size,
                              hipStream_t stream) {
    const float* y   = (const float*)d_in[0];
    const float* k   = (const float*)d_in[1];
    const float* w   = (const float*)d_in[2];
    const float* phi = (const float*)d_in[3];
    const float* wts = (const float*)d_in[4];
    float* out = (float*)d_out;

    // workspace: S = 19 imgs (pass-1) | T = 19 imgs (col-FFT out).
    // P (inverse pass-1 out, 6 imgs) reuses S[0..5] (S dead after col_fft).
    const size_t needed = (size_t)38 * NPIX * sizeof(float2);  // 76 MB
    if (ws_size < needed) return;  // clean incorrectness signal, never OOB
    float2* S = (float2*)d_ws;
    float2* T = S + (size_t)19 * NPIX;
    float2* P = S;

    // pass 1: row FFTs (y/phi packed; K/G sparse rows synthesized in-block,
    // G autocorr computed in-block — no separate prep launch, no memset)
    fwd_fft_all<<<6271, 128, 0, stream>>>(y, phi, w, k, wts, S);

    // fused transpose + column FFT: S -> T (zero rows of K/G synthesized)
    col_fft<-1><<<19 * 64, 1024, 0, stream>>>(S, T);

    // Wiener combine + inverse row-FFT: T -> P (mirror rows shared via LDS)
    combine_ifft<<<dim3(257, 6), 256, 0, stream>>>(T, w, P);

    // fused transpose + inverse column FFT + real unpack: P -> out
    col_ifft_unpack<<<6 * 64, 1024, 0, stream>>>(P, out);
}